// Round 8
// baseline (300.326 us; speedup 1.0000x reference)
//
#include <hip/hip_runtime.h>
#include <stdint.h>

#define AS1 __attribute__((address_space(1)))
#define AS3 __attribute__((address_space(3)))

typedef short v8s __attribute__((ext_vector_type(8)));
typedef float v4f __attribute__((ext_vector_type(4)));

__device__ __forceinline__ float b2f(unsigned short u) {
  return __uint_as_float(((unsigned int)u) << 16);
}
__device__ __forceinline__ unsigned short f2bu(float f) {
  unsigned int u = __float_as_uint(f);
  u += 0x7fffu + ((u >> 16) & 1u);
  return (unsigned short)(u >> 16);
}

__device__ __forceinline__ void gload16(const void* g, const void* l) {
  __builtin_amdgcn_global_load_lds(
      (const AS1 void*)(uintptr_t)g,
      (AS3 void*)(unsigned)(uintptr_t)l,
      16, 0, 0);
}

#define BAR __builtin_amdgcn_s_barrier()
#define VMC0 asm volatile("s_waitcnt vmcnt(0)" ::: "memory")

// ---------------------------------------------------------------------------
// Transpose + f32->bf16 convert: src [K][N] f32 (ld=N) -> dst [N][K] bf16
// ---------------------------------------------------------------------------
__global__ __launch_bounds__(256)
void transpose_cvt(const float* __restrict__ src, long long srcZ,
                   unsigned short* __restrict__ dst, long long dstZ, int ld_dst,
                   int K, int N)
{
  __shared__ float t[32][33];
  const int e = blockIdx.z;
  src += (long long)e * srcZ;
  dst += (long long)e * dstZ;
  const int k0 = blockIdx.y * 32, n0 = blockIdx.x * 32;
  const int tx = threadIdx.x & 31, ty = threadIdx.x >> 5;
#pragma unroll
  for (int r = 0; r < 32; r += 8)
    t[ty + r][tx] = src[(long long)(k0 + ty + r) * N + n0 + tx];
  __syncthreads();
#pragma unroll
  for (int r = 0; r < 32; r += 8) {
    const int n = ty + r;
    dst[(long long)(n0 + n) * ld_dst + k0 + tx] = f2bu(t[tx][n]);
  }
}

__global__ __launch_bounds__(256)
void cvt_f32_bf16(const float* __restrict__ src, unsigned short* __restrict__ dst, int n)
{
  const int i = (blockIdx.x * 256 + threadIdx.x) * 4;
  if (i >= n) return;
  float4 v = *(const float4*)(src + i);
  ushort4 o;
  o.x = f2bu(v.x); o.y = f2bu(v.y); o.z = f2bu(v.z); o.w = f2bu(v.w);
  *(ushort4*)(dst + i) = o;
}

// ---------------------------------------------------------------------------
// 256x128 bf16 GEMM, BK=32, double-buffered, 8 waves (4M x 2N), 48 KiB LDS
// -> 2 blocks/CU (16 waves/CU) for implicit cross-block stall hiding.
// T3-minimum schedule: STAGE(next) | ds_read(cur) | MFMA x16 | vmcnt(0) | bar.
// LDS: swizzled 16x32 subtiles (1 KiB each): elem = (rr*32+kg*8)^((rr&8)<<1);
// staging source col pre-swizzled (rule 21).  A: 16 subtiles, B: 8 subtiles.
// EPI 0: bf16 Q/K/V out = acc + bias[col]; out slab = col>>10
// EPI 1: bf16 out = gate * gelu_new(acc + bias[col])  (hs, ld 8192)
// EPI 3: split-K partial: z=0 -> f32 out0, z>0 -> bf16 pbs[z-1]
// ---------------------------------------------------------------------------
#define STAGE3(AsN, BsN) do { \
    gload16(pA1, (AsN) + wA); \
    gload16(pA2, (AsN) + 4096 + wA); \
    gload16(pB,  (BsN) + wA); \
    pA1 += 32; pA2 += 32; pB += 32; \
  } while (0)

#define READF(AsC, BsC) do { \
    _Pragma("unroll") \
    for (int i = 0; i < 4; ++i) \
      af[i] = *(const v8s*)((AsC) + (((wm*4 + i) << 9) | rswz)); \
    _Pragma("unroll") \
    for (int j = 0; j < 4; ++j) \
      bfr[j] = *(const v8s*)((BsC) + (((wn*4 + j) << 9) | rswz)); \
  } while (0)

#define MFMA16 do { \
    __builtin_amdgcn_s_setprio(1); \
    _Pragma("unroll") \
    for (int i = 0; i < 4; ++i) \
      _Pragma("unroll") \
      for (int j = 0; j < 4; ++j) \
        acc[i][j] = __builtin_amdgcn_mfma_f32_16x16x32_bf16(af[i], bfr[j], acc[i][j], 0, 0, 0); \
    __builtin_amdgcn_s_setprio(0); \
  } while (0)

template<int EPI>
__global__ __launch_bounds__(512, 4)
void gemmK(const unsigned short* __restrict__ A, int lda,
           const unsigned short* __restrict__ Bt, int ldb,
           const float* __restrict__ bias,
           void* __restrict__ out0, unsigned short* __restrict__ pbs,
           int kLen, const float* __restrict__ gates)
{
  __shared__ __align__(16) unsigned short lds[24576];   // 48 KiB
  unsigned short* As0 = lds;            // 16 subtiles = 8192 elems
  unsigned short* As1 = lds + 8192;
  unsigned short* Bs0 = lds + 16384;    // 8 subtiles = 4096 elems
  unsigned short* Bs1 = lds + 20480;

  const int tid  = threadIdx.x;
  const int lane = tid & 63;
  const int w    = tid >> 6;        // 0..7
  const int wm   = w >> 1;          // 0..3
  const int wn   = w & 1;           // 0..1
  const int m0   = blockIdx.y * 256;
  const int n0   = blockIdx.x * 128;
  const int z    = blockIdx.z;
  const int kBase = (EPI == 3) ? z * kLen : 0;

  // staging: wave w fills A subtiles {w, w+8} and B subtile {w}; lane l -> 16B at l*16
  const int sR = w * 16 + (lane >> 2);
  const int sC = ((lane & 3) * 8) ^ (((lane >> 5) & 1) << 4);   // inverse-swizzled source col
  // read fragment address (within-subtile, swizzled)
  const int rr   = lane & 15;
  const int kg   = lane >> 4;
  const int rswz = (rr * 32 + kg * 8) ^ ((rr & 8) << 1);
  const int wA   = w * 512;

  const unsigned short* pA1 = A + (long long)(m0 + sR) * lda + kBase + sC;
  const unsigned short* pA2 = pA1 + (long long)128 * lda;
  const unsigned short* pB  = Bt + (long long)(n0 + sR) * ldb + kBase + sC;

  v4f acc[4][4] = {};
  v8s af[4], bfr[4];

  const int nt = kLen >> 5;   // K-steps of 32 (always even here)

  // ---- prologue: buf0 <- k-step 0 ----
  STAGE3(As0, Bs0);
  VMC0; BAR;

  for (int t = 0; t < nt; t += 2) {
    // even step: stage buf1 (k=t+1), compute buf0
    STAGE3(As1, Bs1);
    READF(As0, Bs0);
    MFMA16;
    VMC0; BAR;
    // odd step: stage buf0 (k=t+2) if any, compute buf1
    const bool more = (t + 2 < nt);
    if (more) STAGE3(As0, Bs0);
    READF(As1, Bs1);
    MFMA16;
    if (more) { VMC0; BAR; }
  }

  // ---- epilogue ----
  const int lr4 = (lane >> 4) * 4;
  const int lc  = lane & 15;
  const int row0 = m0 + wm * 64;
  const int col0 = n0 + wn * 64;
  float gate = 0.f;
  if (EPI == 1) gate = gates[(m0 >> 10) * 8 + (n0 >> 10)];

#pragma unroll
  for (int i = 0; i < 4; ++i) {
#pragma unroll
    for (int j = 0; j < 4; ++j) {
      const int col = col0 + j * 16 + lc;
#pragma unroll
      for (int r = 0; r < 4; ++r) {
        const int row = row0 + i * 16 + lr4 + r;
        float v = acc[i][j][r];
        if (EPI == 0) {
          v += bias[col];
          const int which = col >> 10;
          ((unsigned short*)out0)[(long long)which * 4194304 + (long long)row * 1024 + (col & 1023)] = f2bu(v);
        } else if (EPI == 1) {
          v += bias[col];
          float u = 0.7978845608028654f * (v + 0.044715f * v * v * v);
          u = fminf(fmaxf(u, -15.f), 15.f);
          float e2 = __expf(2.f * u);
          float th = (e2 - 1.f) / (e2 + 1.f);
          ((unsigned short*)out0)[(long long)row * 8192 + col] = f2bu(gate * 0.5f * v * (1.f + th));
        } else {
          if (z == 0) ((float*)out0)[(long long)row * 1024 + col] = v;
          else pbs[(long long)(z - 1) * 4194304 + (long long)row * 1024 + col] = f2bu(v);
        }
      }
    }
  }
}

// ---------------------------------------------------------------------------
// out = out + pb0 + pb1 + pb2 (bf16 partials) + bias2[b][n]
// ---------------------------------------------------------------------------
__global__ __launch_bounds__(256)
void reduce3(float* __restrict__ out, const unsigned short* __restrict__ pb,
             const float* __restrict__ bias2)
{
  const int i = (blockIdx.x * 256 + threadIdx.x) * 4;
  const int b = i >> 20;
  const int n = i & 1023;
  float4 a = *(const float4*)(out + i);
  ushort4 p0 = *(const ushort4*)(pb + i);
  ushort4 p1 = *(const ushort4*)(pb + 4194304 + i);
  ushort4 p2 = *(const ushort4*)(pb + 8388608 + i);
  float4 bb = *(const float4*)(bias2 + b * 1024 + n);
  a.x += b2f(p0.x) + b2f(p1.x) + b2f(p2.x) + bb.x;
  a.y += b2f(p0.y) + b2f(p1.y) + b2f(p2.y) + bb.y;
  a.z += b2f(p0.z) + b2f(p1.z) + b2f(p2.z) + bb.z;
  a.w += b2f(p0.w) + b2f(p1.w) + b2f(p2.w) + bb.w;
  *(float4*)(out + i) = a;
}

// ---------------------------------------------------------------------------
// Per-token cross-head attention (unchanged)
// ---------------------------------------------------------------------------
__global__ __launch_bounds__(256)
void attn_kernel(const unsigned short* __restrict__ Qb,
                 const unsigned short* __restrict__ Kb,
                 const unsigned short* __restrict__ Vb,
                 unsigned short* __restrict__ a)
{
  const int token = blockIdx.x;
  const int b = token >> 10, s = token & 1023;
  __shared__ float Qs[16][65], Ks[16][65], Vs[16][65];
  __shared__ float attn_s[16][17];
  const int t = threadIdx.x;
  const long long base = (long long)token * 1024;

  {
    const int i0 = t * 4;
    const int hh = i0 >> 6, dd = i0 & 63;
    ushort4 qv = *(const ushort4*)(Qb + base + i0);
    ushort4 kv = *(const ushort4*)(Kb + base + i0);
    ushort4 vv = *(const ushort4*)(Vb + base + i0);
    Qs[hh][dd+0]=b2f(qv.x); Qs[hh][dd+1]=b2f(qv.y); Qs[hh][dd+2]=b2f(qv.z); Qs[hh][dd+3]=b2f(qv.w);
    Ks[hh][dd+0]=b2f(kv.x); Ks[hh][dd+1]=b2f(kv.y); Ks[hh][dd+2]=b2f(kv.z); Ks[hh][dd+3]=b2f(kv.w);
    Vs[hh][dd+0]=b2f(vv.x); Vs[hh][dd+1]=b2f(vv.y); Vs[hh][dd+2]=b2f(vv.z); Vs[hh][dd+3]=b2f(vv.w);
  }
  __syncthreads();

  const int q = t >> 4, k = t & 15;
  float sc = 0.f;
#pragma unroll
  for (int d = 0; d < 64; ++d) sc += Qs[q][d] * Ks[k][d];
  sc *= 0.125f;
  float mx = sc;
#pragma unroll
  for (int m = 1; m < 16; m <<= 1) mx = fmaxf(mx, __shfl_xor(mx, m, 64));
  float ex = __expf(sc - mx);
  float sum = ex;
#pragma unroll
  for (int m = 1; m < 16; m <<= 1) sum += __shfl_xor(sum, m, 64);
  attn_s[q][k] = ex / sum;
  __syncthreads();

  const int hd = t & 63;
  const int wv = t >> 6;
#pragma unroll
  for (int r = 0; r < 4; ++r) {
    const int qq = wv * 4 + r;
    float o = 0.f;
#pragma unroll
    for (int kk = 0; kk < 16; ++kk) o += attn_s[qq][kk] * Vs[kk][hd];
    a[(long long)b * 1048576 + (long long)(qq * 64 + (s >> 4)) * 1024 + (s & 15) * 64 + hd] = f2bu(o);
  }
}

// ---------------------------------------------------------------------------
// Gating helpers (unchanged)
// ---------------------------------------------------------------------------
__global__ __launch_bounds__(256)
void col_sum_part(const unsigned short* __restrict__ a, float* __restrict__ part)
{
  const int bx = blockIdx.x;
  const int b = bx >> 2;
  const int d = (bx & 3) * 256 + threadIdx.x;
  const int y = blockIdx.y;
  const unsigned short* p = a + (long long)b * 1048576 + (long long)y * 131072 + d;
  float s = 0.f;
  for (int i = 0; i < 128; ++i) s += b2f(p[i * 1024]);
  part[(y * 4 + b) * 1024 + d] = s;
}

__global__ __launch_bounds__(256)
void gates_bias2(const float* __restrict__ part,
                 const float* __restrict__ Wg,
                 const float* __restrict__ bg,
                 const float* __restrict__ b2,
                 float* __restrict__ gates,
                 float* __restrict__ bias2)
{
  __shared__ float am[4][1024];
  __shared__ float sg[4][8];
  const int t = threadIdx.x;

  for (int i = t; i < 4096; i += 256) {
    const int b = i >> 10, d = i & 1023;
    float s = 0.f;
#pragma unroll
    for (int y = 0; y < 8; ++y) s += part[(y * 4 + b) * 1024 + d];
    am[b][d] = s * (1.f / 1024.f);
  }
  __syncthreads();

  const int pair = t >> 3, subl = t & 7;
  const int b = pair >> 3, e = pair & 7;
  float s = 0.f;
  for (int d = subl * 128; d < subl * 128 + 128; ++d) s += am[b][d] * Wg[d * 8 + e];
#pragma unroll
  for (int m = 1; m < 8; m <<= 1) s += __shfl_xor(s, m, 64);
  if (subl == 0) sg[b][e] = s + bg[e];
  __syncthreads();

  if (t < 4) {
    float mx = -1e30f;
    for (int ee = 0; ee < 8; ++ee) mx = fmaxf(mx, sg[t][ee]);
    float g[8]; float ssum = 0.f;
    for (int ee = 0; ee < 8; ++ee) { g[ee] = __expf(sg[t][ee] - mx); ssum += g[ee]; }
    for (int ee = 0; ee < 8; ++ee) { sg[t][ee] = g[ee] / ssum; gates[t * 8 + ee] = sg[t][ee]; }
  }
  __syncthreads();

  for (int i = t; i < 4096; i += 256) {
    const int bb = i >> 10, n = i & 1023;
    float ss = 0.f;
#pragma unroll
    for (int ee = 0; ee < 8; ++ee) ss += sg[bb][ee] * b2[ee * 1024 + n];
    bias2[i] = ss;
  }
}

// ---------------------------------------------------------------------------
// Host launch
// ---------------------------------------------------------------------------
extern "C" void kernel_launch(void* const* d_in, const int* in_sizes, int n_in,
                              void* d_out, int out_size, void* d_ws, size_t ws_size,
                              hipStream_t stream) {
  const float* x  = (const float*)d_in[0];
  const float* Wq = (const float*)d_in[1];
  const float* bq = (const float*)d_in[2];
  const float* Wk = (const float*)d_in[3];
  const float* bk = (const float*)d_in[4];
  const float* Wv = (const float*)d_in[5];
  const float* bv = (const float*)d_in[6];
  const float* Wg = (const float*)d_in[7];
  const float* bg = (const float*)d_in[8];
  const float* W1 = (const float*)d_in[9];
  const float* b1 = (const float*)d_in[10];
  const float* W2 = (const float*)d_in[11];
  const float* b2 = (const float*)d_in[12];
  float* out = (float*)d_out;

  if (ws_size < (size_t)109300000) return;

  char* ws = (char*)d_ws;
  unsigned short* xb   = (unsigned short*)(ws + 0);
  unsigned short* Wqt  = (unsigned short*)(ws + 8388608);     // [3072][1024]
  unsigned short* Qb   = (unsigned short*)(ws + 14680064);    // Q,K,V [3][4096][1024]
  unsigned short* hs   = (unsigned short*)(ws + 0);           // [4096][8192]
  unsigned short* abuf = (unsigned short*)(ws + 67108864);    // [4096][1024]
  unsigned short* pbs  = (unsigned short*)(ws + 67108864);    // 3x[4096][1024] bf16 (after EPI1)
  unsigned short* W1t  = (unsigned short*)(ws + 75497472);    // [8192][1024]
  unsigned short* W2t  = (unsigned short*)(ws + 92274688);    // [1024][8192]
  float* part  = (float*)(ws + 109051904);
  float* gates = (float*)(ws + 109051904 + 131072);
  float* bias2 = (float*)(ws + 109051904 + 131072 + 512);
  float* bqkv  = (float*)(ws + 109051904 + 131072 + 512 + 16384);

  dim3 tb(256);

  transpose_cvt<<<dim3(32,32,1), tb, 0, stream>>>(Wq, 0LL, Wqt,           0LL, 1024, 1024, 1024);
  transpose_cvt<<<dim3(32,32,1), tb, 0, stream>>>(Wk, 0LL, Wqt + 1048576, 0LL, 1024, 1024, 1024);
  transpose_cvt<<<dim3(32,32,1), tb, 0, stream>>>(Wv, 0LL, Wqt + 2097152, 0LL, 1024, 1024, 1024);
  transpose_cvt<<<dim3(32,32,8), tb, 0, stream>>>(W1, 1048576LL, W1t, 1048576LL, 1024, 1024, 1024);
  transpose_cvt<<<dim3(32,32,8), tb, 0, stream>>>(W2, 1048576LL, W2t, 1024LL,    8192, 1024, 1024);
  cvt_f32_bf16<<<4096, tb, 0, stream>>>(x, xb, 4194304);
  hipMemcpyAsync(bqkv,        bq, 4096, hipMemcpyDeviceToDevice, stream);
  hipMemcpyAsync(bqkv + 1024, bk, 4096, hipMemcpyDeviceToDevice, stream);
  hipMemcpyAsync(bqkv + 2048, bv, 4096, hipMemcpyDeviceToDevice, stream);

  // QKV: M=4096, N=3072 (flat), K=1024
  gemmK<0><<<dim3(24,16,1), 512, 0, stream>>>(xb, 1024, Wqt, 1024, bqkv,
                                              Qb, nullptr, 1024, nullptr);
  // Attention -> scrambled a
  attn_kernel<<<4096, tb, 0, stream>>>(Qb, Qb + 4194304, Qb + 8388608, abuf);
  // Gating
  col_sum_part<<<dim3(16,8), tb, 0, stream>>>(abuf, part);
  gates_bias2<<<1, tb, 0, stream>>>(part, Wg, bg, b2, gates, bias2);
  // Expert up-proj + gelu + gate: M=4096, N=8192 (flat experts), K=1024
  gemmK<1><<<dim3(64,16,1), 512, 0, stream>>>(abuf, 1024, W1t, 1024, b1,
                                              hs, nullptr, 1024, gates);
  // Final down-proj: M=4096, N=1024, K=8192, split-K 4 (z=0 -> out f32, z>0 -> bf16 partials)
  gemmK<3><<<dim3(8,16,4), 512, 0, stream>>>(hs, 8192, W2t, 8192, nullptr,
                                             out, pbs, 2048, nullptr);
  reduce3<<<4096, tb, 0, stream>>>(out, pbs, bias2);
}

// Round 9
// 270.141 us; speedup vs baseline: 1.1117x; 1.1117x over previous
//
#include <hip/hip_runtime.h>
#include <stdint.h>

#define AS1 __attribute__((address_space(1)))
#define AS3 __attribute__((address_space(3)))

typedef short v8s __attribute__((ext_vector_type(8)));
typedef float v4f __attribute__((ext_vector_type(4)));

__device__ __forceinline__ float b2f(unsigned short u) {
  return __uint_as_float(((unsigned int)u) << 16);
}
__device__ __forceinline__ unsigned short f2bu(float f) {
  unsigned int u = __float_as_uint(f);
  u += 0x7fffu + ((u >> 16) & 1u);
  return (unsigned short)(u >> 16);
}

__device__ __forceinline__ void gload16(const void* g, const void* l) {
  __builtin_amdgcn_global_load_lds(
      (const AS1 void*)(uintptr_t)g,
      (AS3 void*)(unsigned)(uintptr_t)l,
      16, 0, 0);
}

#define BAR __builtin_amdgcn_s_barrier()
#define VMC4 asm volatile("s_waitcnt vmcnt(4)" ::: "memory")
#define VMC0 asm volatile("s_waitcnt vmcnt(0)" ::: "memory")

// ---------------------------------------------------------------------------
// Transpose + f32->bf16, 64x64 tiles: src [K][N] f32 -> dst [N][K] bf16.
// float4 loads (256B/row segment), ushort4 stores (128B segments),
// LDS [64][65] -> ~2-way read aliasing (free, m136).  grid (N/64, K/64, Z).
// ---------------------------------------------------------------------------
__global__ __launch_bounds__(256)
void transpose_cvt(const float* __restrict__ src, long long srcZ,
                   unsigned short* __restrict__ dst, long long dstZ, int ld_dst,
                   int K, int N)
{
  __shared__ float t[64][65];
  const int e = blockIdx.z;
  src += (long long)e * srcZ;
  dst += (long long)e * dstZ;
  const int k0 = blockIdx.y * 64, n0 = blockIdx.x * 64;
  const int tr  = threadIdx.x >> 4;        // 0..15
  const int tc4 = (threadIdx.x & 15) * 4;  // 0,4,...,60
#pragma unroll
  for (int p = 0; p < 4; ++p) {
    float4 v = *(const float4*)(src + (long long)(k0 + tr + p * 16) * N + n0 + tc4);
    t[tr + p * 16][tc4 + 0] = v.x;
    t[tr + p * 16][tc4 + 1] = v.y;
    t[tr + p * 16][tc4 + 2] = v.z;
    t[tr + p * 16][tc4 + 3] = v.w;
  }
  __syncthreads();
#pragma unroll
  for (int p = 0; p < 4; ++p) {
    const int n = tr + p * 16;
    ushort4 o;
    o.x = f2bu(t[tc4 + 0][n]);
    o.y = f2bu(t[tc4 + 1][n]);
    o.z = f2bu(t[tc4 + 2][n]);
    o.w = f2bu(t[tc4 + 3][n]);
    *(ushort4*)(dst + (long long)(n0 + n) * ld_dst + k0 + tc4) = o;
  }
}

__global__ __launch_bounds__(256)
void cvt_f32_bf16(const float* __restrict__ src, unsigned short* __restrict__ dst, int n)
{
  const int i = (blockIdx.x * 256 + threadIdx.x) * 4;
  if (i >= n) return;
  float4 v = *(const float4*)(src + i);
  ushort4 o;
  o.x = f2bu(v.x); o.y = f2bu(v.y); o.z = f2bu(v.z); o.w = f2bu(v.w);
  *(ushort4*)(dst + i) = o;
}

// ---------------------------------------------------------------------------
// 256x256 bf16 GEMM, BK=64, 8 waves (2Mx4N), 4 phases per 2-K-tile iteration.
// (R7 kernel, verbatim — best verified config: 94us/GEMM, conflicts 0.)
// st_16x32-swizzled subtiled LDS ([row/16][col/32][16][32], byte^=((b>>9)&1)<<5).
// EPI 0: bf16 Q/K/V out = acc + bias[col]; out slab = col>>10
// EPI 1: bf16 out = gate * gelu_new(acc + bias[col])  (hs, ld 8192)
// EPI 3: split-K partial: z=0 -> f32 out0, z>0 -> bf16 pbs[z-1]
// ---------------------------------------------------------------------------
template<int MH>
__device__ __forceinline__ void read_a(v8s af[4][2],
    const unsigned short* pa, int wm, int rswz)
{
#pragma unroll
  for (int i = 0; i < 4; ++i)
#pragma unroll
    for (int s = 0; s < 2; ++s)
      af[i][s] = *(const v8s*)(pa + MH*8192 + ((((wm*4 + i)*2 + s) << 9) | rswz));
}

template<int NH>
__device__ __forceinline__ void read_b(v8s bfr[2][2],
    const unsigned short* pb, int wn, int rswz)
{
#pragma unroll
  for (int j = 0; j < 2; ++j)
#pragma unroll
    for (int s = 0; s < 2; ++s)
      bfr[j][s] = *(const v8s*)(pb + NH*8192 + ((((wn*2 + j)*2 + s) << 9) | rswz));
}

template<int MH, int NH>
__device__ __forceinline__ void quad_mfma(v4f acc[8][4], v8s af[4][2], v8s bfr[2][2])
{
  __builtin_amdgcn_s_setprio(1);
#pragma unroll
  for (int i = 0; i < 4; ++i)
#pragma unroll
    for (int j = 0; j < 2; ++j)
#pragma unroll
      for (int s = 0; s < 2; ++s)
        acc[MH*4+i][NH*2+j] = __builtin_amdgcn_mfma_f32_16x16x32_bf16(
            af[i][s], bfr[j][s], acc[MH*4+i][NH*2+j], 0, 0, 0);
  __builtin_amdgcn_s_setprio(0);
}

#define STAGE(G, LD, LDSBASE, GROW0, KT) do { \
    gload16((G) + (long long)((GROW0) + sRow) * (LD) + (KT) + sCol, \
            (LDSBASE) + w512); \
    gload16((G) + (long long)((GROW0) + 64 + sRow) * (LD) + (KT) + sCol, \
            (LDSBASE) + 4096 + w512); \
  } while (0)

template<int EPI>
__global__ __launch_bounds__(512, 2)
void gemm256(const unsigned short* __restrict__ A, int lda,
             const unsigned short* __restrict__ Bt, int ldb,
             const float* __restrict__ bias,
             void* __restrict__ out0, unsigned short* __restrict__ pbs,
             int kLen, const float* __restrict__ gates)
{
  __shared__ __align__(16) unsigned short lds[65536];   // 128 KiB
  unsigned short* As0 = lds;
  unsigned short* As1 = lds + 16384;
  unsigned short* Bs0 = lds + 32768;
  unsigned short* Bs1 = lds + 49152;

  const int tid  = threadIdx.x;
  const int lane = tid & 63;
  const int w    = tid >> 6;        // 0..7
  const int wm   = w >> 2;          // 0..1
  const int wn   = w & 3;           // 0..3
  const int m0   = blockIdx.y * 256;
  const int n0   = blockIdx.x * 256;
  const int z    = blockIdx.z;
  const int kBase = (EPI == 3) ? z * kLen : 0;

  const int sRow = (w >> 1) * 16 + (lane >> 2);
  const int sCol = (w & 1) * 32 + (((lane & 3) * 8) ^ (((lane >> 5) & 1) << 4));
  const int rr   = lane & 15;
  const int kgrp = lane >> 4;
  const int rswz = (rr * 32 + kgrp * 8) ^ ((rr & 8) << 1);
  const int w512 = w * 512;

  v4f acc[8][4] = {};
  v8s af[4][2], blo[2][2], bhi[2][2];

  const int iters = kLen >> 7;   // 2 K-tiles (BK=64) per iteration

  // ---- prologue: buf0 <- T0 (8 gloads), buf1 <- T1 A-lo/B-lo (4 gloads) ----
  STAGE(A,  lda, As0,        m0,       kBase);
  STAGE(A,  lda, As0 + 8192, m0 + 128, kBase);
  STAGE(Bt, ldb, Bs0,        n0,       kBase);
  STAGE(Bt, ldb, Bs0 + 8192, n0 + 128, kBase);
  STAGE(A,  lda, As1,        m0,       kBase + 64);
  STAGE(Bt, ldb, Bs1,        n0,       kBase + 64);
  VMC4;   // buf0 landed; buf1-lo (4) in flight
  BAR;

  for (int it = 0; it < iters; ++it) {
    const bool nl = (it != iters - 1);
    const int k0t = kBase + it * 128;
    const int kT1 = k0t + 64, kT2 = k0t + 128, kT3 = k0t + 192;

    // P1: buf0 Q(0,0)+(0,1) | stage buf1-hi (T+1)
    read_a<0>(af, As0, wm, rswz);
    read_b<0>(blo, Bs0, wn, rswz);
    read_b<1>(bhi, Bs0, wn, rswz);
    STAGE(A,  lda, As1 + 8192, m0 + 128, kT1);
    STAGE(Bt, ldb, Bs1 + 8192, n0 + 128, kT1);
    BAR;
    quad_mfma<0,0>(acc, af, blo);
    quad_mfma<0,1>(acc, af, bhi);
    BAR;
    // P2: buf0 Q(1,0)+(1,1) | stage buf0-lo (T+2) | VMC: buf1 landed
    read_a<1>(af, As0, wm, rswz);
    if (nl) { STAGE(A, lda, As0, m0, kT2); STAGE(Bt, ldb, Bs0, n0, kT2); }
    BAR;
    quad_mfma<1,0>(acc, af, blo);
    quad_mfma<1,1>(acc, af, bhi);
    if (nl) { VMC4; } else { VMC0; }
    BAR;
    // P3: buf1 Q(0,0)+(0,1) | stage buf0-hi (T+2)
    read_a<0>(af, As1, wm, rswz);
    read_b<0>(blo, Bs1, wn, rswz);
    read_b<1>(bhi, Bs1, wn, rswz);
    if (nl) { STAGE(A, lda, As0 + 8192, m0 + 128, kT2); STAGE(Bt, ldb, Bs0 + 8192, n0 + 128, kT2); }
    BAR;
    quad_mfma<0,0>(acc, af, blo);
    quad_mfma<0,1>(acc, af, bhi);
    BAR;
    // P4: buf1 Q(1,0)+(1,1) | stage buf1-lo (T+3) | VMC: buf0(T+2) landed
    read_a<1>(af, As1, wm, rswz);
    if (nl) { STAGE(A, lda, As1, m0, kT3); STAGE(Bt, ldb, Bs1, n0, kT3); }
    BAR;
    quad_mfma<1,0>(acc, af, blo);
    quad_mfma<1,1>(acc, af, bhi);
    if (nl) VMC4;
    BAR;
  }

  // ---- epilogue ----
  const int lr4 = (lane >> 4) * 4;
  const int lc  = lane & 15;
  float gate = 0.f;
  if (EPI == 1) gate = gates[(m0 >> 10) * 8 + (n0 >> 10)];

#pragma unroll
  for (int mi = 0; mi < 8; ++mi) {
    const int rowb = m0 + (mi >> 2) * 128 + wm * 64 + (mi & 3) * 16 + lr4;
#pragma unroll
    for (int nj = 0; nj < 4; ++nj) {
      const int col = n0 + (nj >> 1) * 128 + wn * 32 + (nj & 1) * 16 + lc;
#pragma unroll
      for (int r = 0; r < 4; ++r) {
        const int row = rowb + r;
        float v = acc[mi][nj][r];
        if (EPI == 0) {
          v += bias[col];
          const int which = col >> 10;
          ((unsigned short*)out0)[(long long)which * 4194304 + (long long)row * 1024 + (col & 1023)] = f2bu(v);
        } else if (EPI == 1) {
          v += bias[col];
          float u = 0.7978845608028654f * (v + 0.044715f * v * v * v);
          u = fminf(fmaxf(u, -15.f), 15.f);
          float e2 = __expf(2.f * u);
          float th = (e2 - 1.f) / (e2 + 1.f);
          ((unsigned short*)out0)[(long long)row * 8192 + col] = f2bu(gate * 0.5f * v * (1.f + th));
        } else {
          if (z == 0) ((float*)out0)[(long long)row * 1024 + col] = v;
          else pbs[(long long)(z - 1) * 4194304 + (long long)row * 1024 + col] = f2bu(v);
        }
      }
    }
  }
}

// ---------------------------------------------------------------------------
// out = out + pb0 + pb1 + pb2 (bf16 partials) + bias2[b][n]
// ---------------------------------------------------------------------------
__global__ __launch_bounds__(256)
void reduce3(float* __restrict__ out, const unsigned short* __restrict__ pb,
             const float* __restrict__ bias2)
{
  const int i = (blockIdx.x * 256 + threadIdx.x) * 4;
  const int b = i >> 20;
  const int n = i & 1023;
  float4 a = *(const float4*)(out + i);
  ushort4 p0 = *(const ushort4*)(pb + i);
  ushort4 p1 = *(const ushort4*)(pb + 4194304 + i);
  ushort4 p2 = *(const ushort4*)(pb + 8388608 + i);
  float4 bb = *(const float4*)(bias2 + b * 1024 + n);
  a.x += b2f(p0.x) + b2f(p1.x) + b2f(p2.x) + bb.x;
  a.y += b2f(p0.y) + b2f(p1.y) + b2f(p2.y) + bb.y;
  a.z += b2f(p0.z) + b2f(p1.z) + b2f(p2.z) + bb.z;
  a.w += b2f(p0.w) + b2f(p1.w) + b2f(p2.w) + bb.w;
  *(float4*)(out + i) = a;
}

// ---------------------------------------------------------------------------
// Per-token cross-head attention (unchanged)
// ---------------------------------------------------------------------------
__global__ __launch_bounds__(256)
void attn_kernel(const unsigned short* __restrict__ Qb,
                 const unsigned short* __restrict__ Kb,
                 const unsigned short* __restrict__ Vb,
                 unsigned short* __restrict__ a)
{
  const int token = blockIdx.x;
  const int b = token >> 10, s = token & 1023;
  __shared__ float Qs[16][65], Ks[16][65], Vs[16][65];
  __shared__ float attn_s[16][17];
  const int t = threadIdx.x;
  const long long base = (long long)token * 1024;

  {
    const int i0 = t * 4;
    const int hh = i0 >> 6, dd = i0 & 63;
    ushort4 qv = *(const ushort4*)(Qb + base + i0);
    ushort4 kv = *(const ushort4*)(Kb + base + i0);
    ushort4 vv = *(const ushort4*)(Vb + base + i0);
    Qs[hh][dd+0]=b2f(qv.x); Qs[hh][dd+1]=b2f(qv.y); Qs[hh][dd+2]=b2f(qv.z); Qs[hh][dd+3]=b2f(qv.w);
    Ks[hh][dd+0]=b2f(kv.x); Ks[hh][dd+1]=b2f(kv.y); Ks[hh][dd+2]=b2f(kv.z); Ks[hh][dd+3]=b2f(kv.w);
    Vs[hh][dd+0]=b2f(vv.x); Vs[hh][dd+1]=b2f(vv.y); Vs[hh][dd+2]=b2f(vv.z); Vs[hh][dd+3]=b2f(vv.w);
  }
  __syncthreads();

  const int q = t >> 4, k = t & 15;
  float sc = 0.f;
#pragma unroll
  for (int d = 0; d < 64; ++d) sc += Qs[q][d] * Ks[k][d];
  sc *= 0.125f;
  float mx = sc;
#pragma unroll
  for (int m = 1; m < 16; m <<= 1) mx = fmaxf(mx, __shfl_xor(mx, m, 64));
  float ex = __expf(sc - mx);
  float sum = ex;
#pragma unroll
  for (int m = 1; m < 16; m <<= 1) sum += __shfl_xor(sum, m, 64);
  attn_s[q][k] = ex / sum;
  __syncthreads();

  const int hd = t & 63;
  const int wv = t >> 6;
#pragma unroll
  for (int r = 0; r < 4; ++r) {
    const int qq = wv * 4 + r;
    float o = 0.f;
#pragma unroll
    for (int kk = 0; kk < 16; ++kk) o += attn_s[qq][kk] * Vs[kk][hd];
    a[(long long)b * 1048576 + (long long)(qq * 64 + (s >> 4)) * 1024 + (s & 15) * 64 + hd] = f2bu(o);
  }
}

// ---------------------------------------------------------------------------
// Gating helpers (unchanged)
// ---------------------------------------------------------------------------
__global__ __launch_bounds__(256)
void col_sum_part(const unsigned short* __restrict__ a, float* __restrict__ part)
{
  const int bx = blockIdx.x;
  const int b = bx >> 2;
  const int d = (bx & 3) * 256 + threadIdx.x;
  const int y = blockIdx.y;
  const unsigned short* p = a + (long long)b * 1048576 + (long long)y * 131072 + d;
  float s = 0.f;
  for (int i = 0; i < 128; ++i) s += b2f(p[i * 1024]);
  part[(y * 4 + b) * 1024 + d] = s;
}

__global__ __launch_bounds__(256)
void gates_bias2(const float* __restrict__ part,
                 const float* __restrict__ Wg,
                 const float* __restrict__ bg,
                 const float* __restrict__ b2,
                 float* __restrict__ gates,
                 float* __restrict__ bias2)
{
  __shared__ float am[4][1024];
  __shared__ float sg[4][8];
  const int t = threadIdx.x;

  for (int i = t; i < 4096; i += 256) {
    const int b = i >> 10, d = i & 1023;
    float s = 0.f;
#pragma unroll
    for (int y = 0; y < 8; ++y) s += part[(y * 4 + b) * 1024 + d];
    am[b][d] = s * (1.f / 1024.f);
  }
  __syncthreads();

  const int pair = t >> 3, subl = t & 7;
  const int b = pair >> 3, e = pair & 7;
  float s = 0.f;
  for (int d = subl * 128; d < subl * 128 + 128; ++d) s += am[b][d] * Wg[d * 8 + e];
#pragma unroll
  for (int m = 1; m < 8; m <<= 1) s += __shfl_xor(s, m, 64);
  if (subl == 0) sg[b][e] = s + bg[e];
  __syncthreads();

  if (t < 4) {
    float mx = -1e30f;
    for (int ee = 0; ee < 8; ++ee) mx = fmaxf(mx, sg[t][ee]);
    float g[8]; float ssum = 0.f;
    for (int ee = 0; ee < 8; ++ee) { g[ee] = __expf(sg[t][ee] - mx); ssum += g[ee]; }
    for (int ee = 0; ee < 8; ++ee) { sg[t][ee] = g[ee] / ssum; gates[t * 8 + ee] = sg[t][ee]; }
  }
  __syncthreads();

  for (int i = t; i < 4096; i += 256) {
    const int bb = i >> 10, n = i & 1023;
    float ss = 0.f;
#pragma unroll
    for (int ee = 0; ee < 8; ++ee) ss += sg[bb][ee] * b2[ee * 1024 + n];
    bias2[i] = ss;
  }
}

// ---------------------------------------------------------------------------
// Host launch
// ---------------------------------------------------------------------------
extern "C" void kernel_launch(void* const* d_in, const int* in_sizes, int n_in,
                              void* d_out, int out_size, void* d_ws, size_t ws_size,
                              hipStream_t stream) {
  const float* x  = (const float*)d_in[0];
  const float* Wq = (const float*)d_in[1];
  const float* bq = (const float*)d_in[2];
  const float* Wk = (const float*)d_in[3];
  const float* bk = (const float*)d_in[4];
  const float* Wv = (const float*)d_in[5];
  const float* bv = (const float*)d_in[6];
  const float* Wg = (const float*)d_in[7];
  const float* bg = (const float*)d_in[8];
  const float* W1 = (const float*)d_in[9];
  const float* b1 = (const float*)d_in[10];
  const float* W2 = (const float*)d_in[11];
  const float* b2 = (const float*)d_in[12];
  float* out = (float*)d_out;

  if (ws_size < (size_t)109300000) return;

  char* ws = (char*)d_ws;
  unsigned short* xb   = (unsigned short*)(ws + 0);
  unsigned short* Wqt  = (unsigned short*)(ws + 8388608);     // [3072][1024]
  unsigned short* Qb   = (unsigned short*)(ws + 14680064);    // Q,K,V [3][4096][1024]
  unsigned short* hs   = (unsigned short*)(ws + 0);           // [4096][8192]
  unsigned short* abuf = (unsigned short*)(ws + 67108864);    // [4096][1024]
  unsigned short* pbs  = (unsigned short*)(ws + 67108864);    // 3x[4096][1024] bf16 (after EPI1)
  unsigned short* W1t  = (unsigned short*)(ws + 75497472);    // [8192][1024]
  unsigned short* W2t  = (unsigned short*)(ws + 92274688);    // [1024][8192]
  float* part  = (float*)(ws + 109051904);
  float* gates = (float*)(ws + 109051904 + 131072);
  float* bias2 = (float*)(ws + 109051904 + 131072 + 512);
  float* bqkv  = (float*)(ws + 109051904 + 131072 + 512 + 16384);

  dim3 tb(256);

  transpose_cvt<<<dim3(16,16,1), tb, 0, stream>>>(Wq, 0LL, Wqt,           0LL, 1024, 1024, 1024);
  transpose_cvt<<<dim3(16,16,1), tb, 0, stream>>>(Wk, 0LL, Wqt + 1048576, 0LL, 1024, 1024, 1024);
  transpose_cvt<<<dim3(16,16,1), tb, 0, stream>>>(Wv, 0LL, Wqt + 2097152, 0LL, 1024, 1024, 1024);
  transpose_cvt<<<dim3(16,16,8), tb, 0, stream>>>(W1, 1048576LL, W1t, 1048576LL, 1024, 1024, 1024);
  transpose_cvt<<<dim3(16,16,8), tb, 0, stream>>>(W2, 1048576LL, W2t, 1024LL,    8192, 1024, 1024);
  cvt_f32_bf16<<<4096, tb, 0, stream>>>(x, xb, 4194304);
  hipMemcpyAsync(bqkv,        bq, 4096, hipMemcpyDeviceToDevice, stream);
  hipMemcpyAsync(bqkv + 1024, bk, 4096, hipMemcpyDeviceToDevice, stream);
  hipMemcpyAsync(bqkv + 2048, bv, 4096, hipMemcpyDeviceToDevice, stream);

  // QKV: M=4096, N=3072 (flat), K=1024
  gemm256<0><<<dim3(12,16,1), 512, 0, stream>>>(xb, 1024, Wqt, 1024, bqkv,
                                                Qb, nullptr, 1024, nullptr);
  // Attention -> scrambled a
  attn_kernel<<<4096, tb, 0, stream>>>(Qb, Qb + 4194304, Qb + 8388608, abuf);
  // Gating
  col_sum_part<<<dim3(16,8), tb, 0, stream>>>(abuf, part);
  gates_bias2<<<1, tb, 0, stream>>>(part, Wg, bg, b2, gates, bias2);
  // Expert up-proj + gelu + gate: M=4096, N=8192 (flat experts), K=1024
  gemm256<1><<<dim3(32,16,1), 512, 0, stream>>>(abuf, 1024, W1t, 1024, b1,
                                                hs, nullptr, 1024, gates);
  // Final down-proj: M=4096, N=1024, K=8192, split-K 4 (z=0 -> out f32, z>0 -> bf16 partials)
  gemm256<3><<<dim3(4,16,4), 512, 0, stream>>>(hs, 8192, W2t, 8192, nullptr,
                                               out, pbs, 2048, nullptr);
  reduce3<<<4096, tb, 0, stream>>>(out, pbs, bias2);
}

// Round 10
// 266.862 us; speedup vs baseline: 1.1254x; 1.0123x over previous
//
#include <hip/hip_runtime.h>
#include <stdint.h>

#define AS1 __attribute__((address_space(1)))
#define AS3 __attribute__((address_space(3)))

typedef short v8s __attribute__((ext_vector_type(8)));
typedef float v4f __attribute__((ext_vector_type(4)));

__device__ __forceinline__ float b2f(unsigned short u) {
  return __uint_as_float(((unsigned int)u) << 16);
}
__device__ __forceinline__ unsigned short f2bu(float f) {
  unsigned int u = __float_as_uint(f);
  u += 0x7fffu + ((u >> 16) & 1u);
  return (unsigned short)(u >> 16);
}

__device__ __forceinline__ void gload16(const void* g, const void* l) {
  __builtin_amdgcn_global_load_lds(
      (const AS1 void*)(uintptr_t)g,
      (AS3 void*)(unsigned)(uintptr_t)l,
      16, 0, 0);
}

#define BAR __builtin_amdgcn_s_barrier()
#define VMC2 asm volatile("s_waitcnt vmcnt(2)" ::: "memory")
#define VMC0 asm volatile("s_waitcnt vmcnt(0)" ::: "memory")

// ---------------------------------------------------------------------------
// Transpose + f32->bf16, 64x64 tiles (R9, verified)
// ---------------------------------------------------------------------------
__global__ __launch_bounds__(256)
void transpose_cvt(const float* __restrict__ src, long long srcZ,
                   unsigned short* __restrict__ dst, long long dstZ, int ld_dst,
                   int K, int N)
{
  __shared__ float t[64][65];
  const int e = blockIdx.z;
  src += (long long)e * srcZ;
  dst += (long long)e * dstZ;
  const int k0 = blockIdx.y * 64, n0 = blockIdx.x * 64;
  const int tr  = threadIdx.x >> 4;
  const int tc4 = (threadIdx.x & 15) * 4;
#pragma unroll
  for (int p = 0; p < 4; ++p) {
    float4 v = *(const float4*)(src + (long long)(k0 + tr + p * 16) * N + n0 + tc4);
    t[tr + p * 16][tc4 + 0] = v.x;
    t[tr + p * 16][tc4 + 1] = v.y;
    t[tr + p * 16][tc4 + 2] = v.z;
    t[tr + p * 16][tc4 + 3] = v.w;
  }
  __syncthreads();
#pragma unroll
  for (int p = 0; p < 4; ++p) {
    const int n = tr + p * 16;
    ushort4 o;
    o.x = f2bu(t[tc4 + 0][n]);
    o.y = f2bu(t[tc4 + 1][n]);
    o.z = f2bu(t[tc4 + 2][n]);
    o.w = f2bu(t[tc4 + 3][n]);
    *(ushort4*)(dst + (long long)(n0 + n) * ld_dst + k0 + tc4) = o;
  }
}

__global__ __launch_bounds__(256)
void cvt_f32_bf16(const float* __restrict__ src, unsigned short* __restrict__ dst, int n)
{
  const int i = (blockIdx.x * 256 + threadIdx.x) * 4;
  if (i >= n) return;
  float4 v = *(const float4*)(src + i);
  ushort4 o;
  o.x = f2bu(v.x); o.y = f2bu(v.y); o.z = f2bu(v.z); o.w = f2bu(v.w);
  *(ushort4*)(dst + i) = o;
}

// ---------------------------------------------------------------------------
// 256x256 bf16 GEMM, BK=64, 8 waves (2Mx4N), m201-granularity 8-phase/iter:
// per K-tile 4 snake-quadrant phases q(0,0)->(0,1)->(1,1)->(1,0), each
// {reads(12/4/8/0 b128) | stage 1 half-tile | BAR | 16 MFMA | [VMC] | BAR}.
// st_16x32-swizzled subtiled LDS; staging source pre-swizzled (rule 21).
// Stage ladder (1 half-tile/phase), WAR-safe (stage phase > last-read phase):
//   ph1:Bs1lo ph2:Bs1hi ph3:As1hi ph4:As0lo' ph5:Bs0lo' ph6:Bs0hi' ph7:As0hi'
//   ph8:As1lo''  | VMC2 at ph4 & ph8 (10 outstanding -> drain consumed buf)
// EPI 0: bf16 Q/K/V out = acc + bias[col]; out slab = col>>10
// EPI 1: bf16 out = gate * gelu_new(acc + bias[col])  (hs, ld 8192)
// EPI 3: split-K partial: z=0 -> f32 out0, z>0 -> bf16 pbs[z-1]
// ---------------------------------------------------------------------------
template<int MH>
__device__ __forceinline__ void read_a(v8s af[4][2],
    const unsigned short* pa, int wm, int rswz)
{
#pragma unroll
  for (int i = 0; i < 4; ++i)
#pragma unroll
    for (int s = 0; s < 2; ++s)
      af[i][s] = *(const v8s*)(pa + MH*8192 + ((((wm*4 + i)*2 + s) << 9) | rswz));
}

template<int NH>
__device__ __forceinline__ void read_b(v8s bfr[2][2],
    const unsigned short* pb, int wn, int rswz)
{
#pragma unroll
  for (int j = 0; j < 2; ++j)
#pragma unroll
    for (int s = 0; s < 2; ++s)
      bfr[j][s] = *(const v8s*)(pb + NH*8192 + ((((wn*2 + j)*2 + s) << 9) | rswz));
}

template<int MH, int NH>
__device__ __forceinline__ void mfma16(v4f acc[8][4], v8s af[4][2], v8s bfr[2][2])
{
  __builtin_amdgcn_s_setprio(1);
#pragma unroll
  for (int i = 0; i < 4; ++i)
#pragma unroll
    for (int j = 0; j < 2; ++j)
#pragma unroll
      for (int s = 0; s < 2; ++s)
        acc[MH*4+i][NH*2+j] = __builtin_amdgcn_mfma_f32_16x16x32_bf16(
            af[i][s], bfr[j][s], acc[MH*4+i][NH*2+j], 0, 0, 0);
  __builtin_amdgcn_s_setprio(0);
}

#define STAGE(G, LD, LDSBASE, GROW0, KT) do { \
    gload16((G) + (long long)((GROW0) + sRow) * (LD) + (KT) + sCol, \
            (LDSBASE) + w512); \
    gload16((G) + (long long)((GROW0) + 64 + sRow) * (LD) + (KT) + sCol, \
            (LDSBASE) + 4096 + w512); \
  } while (0)

template<int EPI>
__global__ __launch_bounds__(512, 2)
void gemm256(const unsigned short* __restrict__ A, int lda,
             const unsigned short* __restrict__ Bt, int ldb,
             const float* __restrict__ bias,
             void* __restrict__ out0, unsigned short* __restrict__ pbs,
             int kLen, const float* __restrict__ gates)
{
  __shared__ __align__(16) unsigned short lds[65536];   // 128 KiB
  unsigned short* As0 = lds;
  unsigned short* As1 = lds + 16384;
  unsigned short* Bs0 = lds + 32768;
  unsigned short* Bs1 = lds + 49152;

  const int tid  = threadIdx.x;
  const int lane = tid & 63;
  const int w    = tid >> 6;        // 0..7
  const int wm   = w >> 2;          // 0..1
  const int wn   = w & 3;           // 0..3
  const int m0   = blockIdx.y * 256;
  const int n0   = blockIdx.x * 256;
  const int z    = blockIdx.z;
  const int kBase = (EPI == 3) ? z * kLen : 0;

  const int sRow = (w >> 1) * 16 + (lane >> 2);
  const int sCol = (w & 1) * 32 + (((lane & 3) * 8) ^ (((lane >> 5) & 1) << 4));
  const int rr   = lane & 15;
  const int kgrp = lane >> 4;
  const int rswz = (rr * 32 + kgrp * 8) ^ ((rr & 8) << 1);
  const int w512 = w * 512;

  v4f acc[8][4] = {};
  v8s af[4][2], b0[2][2], b1[2][2];

  const int iters = kLen >> 7;   // 2 K-tiles (BK=64) per iteration

  // ---- prologue: buf0 full (8 gloads) + buf1 A-lo (2) ----
  STAGE(A,  lda, As0,        m0,       kBase);
  STAGE(A,  lda, As0 + 8192, m0 + 128, kBase);
  STAGE(Bt, ldb, Bs0,        n0,       kBase);
  STAGE(Bt, ldb, Bs0 + 8192, n0 + 128, kBase);
  STAGE(A,  lda, As1,        m0,       kBase + 64);
  VMC2;   // buf0 landed; buf1-Alo in flight
  BAR;

  for (int it = 0; it < iters; ++it) {
    const bool nl = (it != iters - 1);
    const int k0t = kBase + it * 128;
    const int kT1 = k0t + 64, kT2 = k0t + 128, kT3 = k0t + 192;

    // ph1: q(0,0) buf0 | stage Bs1-lo (T+1)
    read_a<0>(af, As0, wm, rswz);
    read_b<0>(b0, Bs0, wn, rswz);
    STAGE(Bt, ldb, Bs1, n0, kT1);
    BAR; mfma16<0,0>(acc, af, b0); BAR;
    // ph2: q(0,1) | stage Bs1-hi (T+1)
    read_b<1>(b1, Bs0, wn, rswz);
    STAGE(Bt, ldb, Bs1 + 8192, n0 + 128, kT1);
    BAR; mfma16<0,1>(acc, af, b1); BAR;
    // ph3: q(1,1) | stage As1-hi (T+1)
    read_a<1>(af, As0, wm, rswz);
    STAGE(A, lda, As1 + 8192, m0 + 128, kT1);
    BAR; mfma16<1,1>(acc, af, b1); BAR;
    // ph4: q(1,0) | stage As0-lo (T+2) | VMC: buf1 landed
    if (nl) STAGE(A, lda, As0, m0, kT2);
    BAR; mfma16<1,0>(acc, af, b0);
    if (nl) { VMC2; } else { VMC0; }
    BAR;
    // ph5: q(0,0) buf1 | stage Bs0-lo (T+2)
    read_a<0>(af, As1, wm, rswz);
    read_b<0>(b0, Bs1, wn, rswz);
    if (nl) STAGE(Bt, ldb, Bs0, n0, kT2);
    BAR; mfma16<0,0>(acc, af, b0); BAR;
    // ph6: q(0,1) | stage Bs0-hi (T+2)
    read_b<1>(b1, Bs1, wn, rswz);
    if (nl) STAGE(Bt, ldb, Bs0 + 8192, n0 + 128, kT2);
    BAR; mfma16<0,1>(acc, af, b1); BAR;
    // ph7: q(1,1) | stage As0-hi (T+2)
    read_a<1>(af, As1, wm, rswz);
    if (nl) STAGE(A, lda, As0 + 8192, m0 + 128, kT2);
    BAR; mfma16<1,1>(acc, af, b1); BAR;
    // ph8: q(1,0) | stage As1-lo (T+3) | VMC2: buf0(T+2) landed
    if (nl) STAGE(A, lda, As1, m0, kT3);
    BAR; mfma16<1,0>(acc, af, b0);
    if (nl) { VMC2; }
    BAR;
  }

  // ---- epilogue ----
  const int lr4 = (lane >> 4) * 4;
  const int lc  = lane & 15;
  float gate = 0.f;
  if (EPI == 1) gate = gates[(m0 >> 10) * 8 + (n0 >> 10)];

#pragma unroll
  for (int mi = 0; mi < 8; ++mi) {
    const int rowb = m0 + (mi >> 2) * 128 + wm * 64 + (mi & 3) * 16 + lr4;
#pragma unroll
    for (int nj = 0; nj < 4; ++nj) {
      const int col = n0 + (nj >> 1) * 128 + wn * 32 + (nj & 1) * 16 + lc;
#pragma unroll
      for (int r = 0; r < 4; ++r) {
        const int row = rowb + r;
        float v = acc[mi][nj][r];
        if (EPI == 0) {
          v += bias[col];
          const int which = col >> 10;
          ((unsigned short*)out0)[(long long)which * 4194304 + (long long)row * 1024 + (col & 1023)] = f2bu(v);
        } else if (EPI == 1) {
          v += bias[col];
          float u = 0.7978845608028654f * (v + 0.044715f * v * v * v);
          u = fminf(fmaxf(u, -15.f), 15.f);
          float e2 = __expf(2.f * u);
          float th = (e2 - 1.f) / (e2 + 1.f);
          ((unsigned short*)out0)[(long long)row * 8192 + col] = f2bu(gate * 0.5f * v * (1.f + th));
        } else {
          if (z == 0) ((float*)out0)[(long long)row * 1024 + col] = v;
          else pbs[(long long)(z - 1) * 4194304 + (long long)row * 1024 + col] = f2bu(v);
        }
      }
    }
  }
}

// ---------------------------------------------------------------------------
// out = out + pb0 + pb1 + pb2 (bf16 partials) + bias2[b][n]
// ---------------------------------------------------------------------------
__global__ __launch_bounds__(256)
void reduce3(float* __restrict__ out, const unsigned short* __restrict__ pb,
             const float* __restrict__ bias2)
{
  const int i = (blockIdx.x * 256 + threadIdx.x) * 4;
  const int b = i >> 20;
  const int n = i & 1023;
  float4 a = *(const float4*)(out + i);
  ushort4 p0 = *(const ushort4*)(pb + i);
  ushort4 p1 = *(const ushort4*)(pb + 4194304 + i);
  ushort4 p2 = *(const ushort4*)(pb + 8388608 + i);
  float4 bb = *(const float4*)(bias2 + b * 1024 + n);
  a.x += b2f(p0.x) + b2f(p1.x) + b2f(p2.x) + bb.x;
  a.y += b2f(p0.y) + b2f(p1.y) + b2f(p2.y) + bb.y;
  a.z += b2f(p0.z) + b2f(p1.z) + b2f(p2.z) + bb.z;
  a.w += b2f(p0.w) + b2f(p1.w) + b2f(p2.w) + bb.w;
  *(float4*)(out + i) = a;
}

// ---------------------------------------------------------------------------
// Per-token cross-head attention (unchanged)
// ---------------------------------------------------------------------------
__global__ __launch_bounds__(256)
void attn_kernel(const unsigned short* __restrict__ Qb,
                 const unsigned short* __restrict__ Kb,
                 const unsigned short* __restrict__ Vb,
                 unsigned short* __restrict__ a)
{
  const int token = blockIdx.x;
  const int b = token >> 10, s = token & 1023;
  __shared__ float Qs[16][65], Ks[16][65], Vs[16][65];
  __shared__ float attn_s[16][17];
  const int t = threadIdx.x;
  const long long base = (long long)token * 1024;

  {
    const int i0 = t * 4;
    const int hh = i0 >> 6, dd = i0 & 63;
    ushort4 qv = *(const ushort4*)(Qb + base + i0);
    ushort4 kv = *(const ushort4*)(Kb + base + i0);
    ushort4 vv = *(const ushort4*)(Vb + base + i0);
    Qs[hh][dd+0]=b2f(qv.x); Qs[hh][dd+1]=b2f(qv.y); Qs[hh][dd+2]=b2f(qv.z); Qs[hh][dd+3]=b2f(qv.w);
    Ks[hh][dd+0]=b2f(kv.x); Ks[hh][dd+1]=b2f(kv.y); Ks[hh][dd+2]=b2f(kv.z); Ks[hh][dd+3]=b2f(kv.w);
    Vs[hh][dd+0]=b2f(vv.x); Vs[hh][dd+1]=b2f(vv.y); Vs[hh][dd+2]=b2f(vv.z); Vs[hh][dd+3]=b2f(vv.w);
  }
  __syncthreads();

  const int q = t >> 4, k = t & 15;
  float sc = 0.f;
#pragma unroll
  for (int d = 0; d < 64; ++d) sc += Qs[q][d] * Ks[k][d];
  sc *= 0.125f;
  float mx = sc;
#pragma unroll
  for (int m = 1; m < 16; m <<= 1) mx = fmaxf(mx, __shfl_xor(mx, m, 64));
  float ex = __expf(sc - mx);
  float sum = ex;
#pragma unroll
  for (int m = 1; m < 16; m <<= 1) sum += __shfl_xor(sum, m, 64);
  attn_s[q][k] = ex / sum;
  __syncthreads();

  const int hd = t & 63;
  const int wv = t >> 6;
#pragma unroll
  for (int r = 0; r < 4; ++r) {
    const int qq = wv * 4 + r;
    float o = 0.f;
#pragma unroll
    for (int kk = 0; kk < 16; ++kk) o += attn_s[qq][kk] * Vs[kk][hd];
    a[(long long)b * 1048576 + (long long)(qq * 64 + (s >> 4)) * 1024 + (s & 15) * 64 + hd] = f2bu(o);
  }
}

// ---------------------------------------------------------------------------
// Gating helpers (unchanged)
// ---------------------------------------------------------------------------
__global__ __launch_bounds__(256)
void col_sum_part(const unsigned short* __restrict__ a, float* __restrict__ part)
{
  const int bx = blockIdx.x;
  const int b = bx >> 2;
  const int d = (bx & 3) * 256 + threadIdx.x;
  const int y = blockIdx.y;
  const unsigned short* p = a + (long long)b * 1048576 + (long long)y * 131072 + d;
  float s = 0.f;
  for (int i = 0; i < 128; ++i) s += b2f(p[i * 1024]);
  part[(y * 4 + b) * 1024 + d] = s;
}

__global__ __launch_bounds__(256)
void gates_bias2(const float* __restrict__ part,
                 const float* __restrict__ Wg,
                 const float* __restrict__ bg,
                 const float* __restrict__ b2,
                 float* __restrict__ gates,
                 float* __restrict__ bias2)
{
  __shared__ float am[4][1024];
  __shared__ float sg[4][8];
  const int t = threadIdx.x;

  for (int i = t; i < 4096; i += 256) {
    const int b = i >> 10, d = i & 1023;
    float s = 0.f;
#pragma unroll
    for (int y = 0; y < 8; ++y) s += part[(y * 4 + b) * 1024 + d];
    am[b][d] = s * (1.f / 1024.f);
  }
  __syncthreads();

  const int pair = t >> 3, subl = t & 7;
  const int b = pair >> 3, e = pair & 7;
  float s = 0.f;
  for (int d = subl * 128; d < subl * 128 + 128; ++d) s += am[b][d] * Wg[d * 8 + e];
#pragma unroll
  for (int m = 1; m < 8; m <<= 1) s += __shfl_xor(s, m, 64);
  if (subl == 0) sg[b][e] = s + bg[e];
  __syncthreads();

  if (t < 4) {
    float mx = -1e30f;
    for (int ee = 0; ee < 8; ++ee) mx = fmaxf(mx, sg[t][ee]);
    float g[8]; float ssum = 0.f;
    for (int ee = 0; ee < 8; ++ee) { g[ee] = __expf(sg[t][ee] - mx); ssum += g[ee]; }
    for (int ee = 0; ee < 8; ++ee) { sg[t][ee] = g[ee] / ssum; gates[t * 8 + ee] = sg[t][ee]; }
  }
  __syncthreads();

  for (int i = t; i < 4096; i += 256) {
    const int bb = i >> 10, n = i & 1023;
    float ss = 0.f;
#pragma unroll
    for (int ee = 0; ee < 8; ++ee) ss += sg[bb][ee] * b2[ee * 1024 + n];
    bias2[i] = ss;
  }
}

// ---------------------------------------------------------------------------
// Host launch
// ---------------------------------------------------------------------------
extern "C" void kernel_launch(void* const* d_in, const int* in_sizes, int n_in,
                              void* d_out, int out_size, void* d_ws, size_t ws_size,
                              hipStream_t stream) {
  const float* x  = (const float*)d_in[0];
  const float* Wq = (const float*)d_in[1];
  const float* bq = (const float*)d_in[2];
  const float* Wk = (const float*)d_in[3];
  const float* bk = (const float*)d_in[4];
  const float* Wv = (const float*)d_in[5];
  const float* bv = (const float*)d_in[6];
  const float* Wg = (const float*)d_in[7];
  const float* bg = (const float*)d_in[8];
  const float* W1 = (const float*)d_in[9];
  const float* b1 = (const float*)d_in[10];
  const float* W2 = (const float*)d_in[11];
  const float* b2 = (const float*)d_in[12];
  float* out = (float*)d_out;

  if (ws_size < (size_t)109300000) return;

  char* ws = (char*)d_ws;
  unsigned short* xb   = (unsigned short*)(ws + 0);
  unsigned short* Wqt  = (unsigned short*)(ws + 8388608);     // [3072][1024]
  unsigned short* Qb   = (unsigned short*)(ws + 14680064);    // Q,K,V [3][4096][1024]
  unsigned short* hs   = (unsigned short*)(ws + 0);           // [4096][8192]
  unsigned short* abuf = (unsigned short*)(ws + 67108864);    // [4096][1024]
  unsigned short* pbs  = (unsigned short*)(ws + 67108864);    // 3x[4096][1024] bf16 (after EPI1)
  unsigned short* W1t  = (unsigned short*)(ws + 75497472);    // [8192][1024]
  unsigned short* W2t  = (unsigned short*)(ws + 92274688);    // [1024][8192]
  float* part  = (float*)(ws + 109051904);
  float* gates = (float*)(ws + 109051904 + 131072);
  float* bias2 = (float*)(ws + 109051904 + 131072 + 512);
  float* bqkv  = (float*)(ws + 109051904 + 131072 + 512 + 16384);

  dim3 tb(256);

  transpose_cvt<<<dim3(16,16,1), tb, 0, stream>>>(Wq, 0LL, Wqt,           0LL, 1024, 1024, 1024);
  transpose_cvt<<<dim3(16,16,1), tb, 0, stream>>>(Wk, 0LL, Wqt + 1048576, 0LL, 1024, 1024, 1024);
  transpose_cvt<<<dim3(16,16,1), tb, 0, stream>>>(Wv, 0LL, Wqt + 2097152, 0LL, 1024, 1024, 1024);
  transpose_cvt<<<dim3(16,16,8), tb, 0, stream>>>(W1, 1048576LL, W1t, 1048576LL, 1024, 1024, 1024);
  transpose_cvt<<<dim3(16,16,8), tb, 0, stream>>>(W2, 1048576LL, W2t, 1024LL,    8192, 1024, 1024);
  cvt_f32_bf16<<<4096, tb, 0, stream>>>(x, xb, 4194304);
  hipMemcpyAsync(bqkv,        bq, 4096, hipMemcpyDeviceToDevice, stream);
  hipMemcpyAsync(bqkv + 1024, bk, 4096, hipMemcpyDeviceToDevice, stream);
  hipMemcpyAsync(bqkv + 2048, bv, 4096, hipMemcpyDeviceToDevice, stream);

  // QKV: M=4096, N=3072 (flat), K=1024
  gemm256<0><<<dim3(12,16,1), 512, 0, stream>>>(xb, 1024, Wqt, 1024, bqkv,
                                                Qb, nullptr, 1024, nullptr);
  // Attention -> scrambled a
  attn_kernel<<<4096, tb, 0, stream>>>(Qb, Qb + 4194304, Qb + 8388608, abuf);
  // Gating
  col_sum_part<<<dim3(16,8), tb, 0, stream>>>(abuf, part);
  gates_bias2<<<1, tb, 0, stream>>>(part, Wg, bg, b2, gates, bias2);
  // Expert up-proj + gelu + gate: M=4096, N=8192 (flat experts), K=1024
  gemm256<1><<<dim3(32,16,1), 512, 0, stream>>>(abuf, 1024, W1t, 1024, b1,
                                                hs, nullptr, 1024, gates);
  // Final down-proj: M=4096, N=1024, K=8192, split-K 4 (z=0 -> out f32, z>0 -> bf16 partials)
  gemm256<3><<<dim3(4,16,4), 512, 0, stream>>>(hs, 8192, W2t, 8192, nullptr,
                                               out, pbs, 2048, nullptr);
  reduce3<<<4096, tb, 0, stream>>>(out, pbs, bias2);
}

// Round 11
// 263.943 us; speedup vs baseline: 1.1378x; 1.0111x over previous
//
#include <hip/hip_runtime.h>
#include <stdint.h>

#define AS1 __attribute__((address_space(1)))
#define AS3 __attribute__((address_space(3)))

typedef short v8s __attribute__((ext_vector_type(8)));
typedef float v4f __attribute__((ext_vector_type(4)));

__device__ __forceinline__ float b2f(unsigned short u) {
  return __uint_as_float(((unsigned int)u) << 16);
}
__device__ __forceinline__ unsigned short f2bu(float f) {
  unsigned int u = __float_as_uint(f);
  u += 0x7fffu + ((u >> 16) & 1u);
  return (unsigned short)(u >> 16);
}

__device__ __forceinline__ void gload16(const void* g, const void* l) {
  __builtin_amdgcn_global_load_lds(
      (const AS1 void*)(uintptr_t)g,
      (AS3 void*)(unsigned)(uintptr_t)l,
      16, 0, 0);
}

#define BAR __builtin_amdgcn_s_barrier()
#define VMC2 asm volatile("s_waitcnt vmcnt(2)" ::: "memory")
#define VMC0 asm volatile("s_waitcnt vmcnt(0)" ::: "memory")

// ---------------------------------------------------------------------------
// Transpose + f32->bf16, 64x64 tiles (R9, verified)
// ---------------------------------------------------------------------------
__global__ __launch_bounds__(256)
void transpose_cvt(const float* __restrict__ src, long long srcZ,
                   unsigned short* __restrict__ dst, long long dstZ, int ld_dst,
                   int K, int N)
{
  __shared__ float t[64][65];
  const int e = blockIdx.z;
  src += (long long)e * srcZ;
  dst += (long long)e * dstZ;
  const int k0 = blockIdx.y * 64, n0 = blockIdx.x * 64;
  const int tr  = threadIdx.x >> 4;
  const int tc4 = (threadIdx.x & 15) * 4;
#pragma unroll
  for (int p = 0; p < 4; ++p) {
    float4 v = *(const float4*)(src + (long long)(k0 + tr + p * 16) * N + n0 + tc4);
    t[tr + p * 16][tc4 + 0] = v.x;
    t[tr + p * 16][tc4 + 1] = v.y;
    t[tr + p * 16][tc4 + 2] = v.z;
    t[tr + p * 16][tc4 + 3] = v.w;
  }
  __syncthreads();
#pragma unroll
  for (int p = 0; p < 4; ++p) {
    const int n = tr + p * 16;
    ushort4 o;
    o.x = f2bu(t[tc4 + 0][n]);
    o.y = f2bu(t[tc4 + 1][n]);
    o.z = f2bu(t[tc4 + 2][n]);
    o.w = f2bu(t[tc4 + 3][n]);
    *(ushort4*)(dst + (long long)(n0 + n) * ld_dst + k0 + tc4) = o;
  }
}

__global__ __launch_bounds__(256)
void cvt_f32_bf16(const float* __restrict__ src, unsigned short* __restrict__ dst, int n)
{
  const int i = (blockIdx.x * 256 + threadIdx.x) * 4;
  if (i >= n) return;
  float4 v = *(const float4*)(src + i);
  ushort4 o;
  o.x = f2bu(v.x); o.y = f2bu(v.y); o.z = f2bu(v.z); o.w = f2bu(v.w);
  *(ushort4*)(dst + i) = o;
}

// ---------------------------------------------------------------------------
// 256x256 bf16 GEMM, BK=64, 8 waves (2Mx4N), 8 phases / 2 K-tiles.
// SINGLE barrier per phase (post-MFMA): waves drift <1 phase, so one wave's
// next-phase ds_reads overlap siblings' MFMA (cross-wave LDS||MFMA overlap).
// Hazard ledger (drift-bounded): RAW via VMC2@ph4/ph8 (FIFO drains exactly
// the consumed buffer: 10 outstanding - 8) + the phase barrier; WAR: every
// region has >=1 barrier strictly between last-read and restage.
// st_16x32-swizzled subtiled LDS; staging source pre-swizzled (rule 21).
// EPI 0: bf16 Q/K/V out = acc + bias[col]; out slab = col>>10
// EPI 1: bf16 out = gate * gelu_new(acc + bias[col])  (hs, ld 8192)
// EPI 3: split-K partial: z=0 -> f32 out0, z>0 -> bf16 pbs[z-1]
// ---------------------------------------------------------------------------
template<int MH>
__device__ __forceinline__ void read_a(v8s af[4][2],
    const unsigned short* pa, int wm, int rswz)
{
#pragma unroll
  for (int i = 0; i < 4; ++i)
#pragma unroll
    for (int s = 0; s < 2; ++s)
      af[i][s] = *(const v8s*)(pa + MH*8192 + ((((wm*4 + i)*2 + s) << 9) | rswz));
}

template<int NH>
__device__ __forceinline__ void read_b(v8s bfr[2][2],
    const unsigned short* pb, int wn, int rswz)
{
#pragma unroll
  for (int j = 0; j < 2; ++j)
#pragma unroll
    for (int s = 0; s < 2; ++s)
      bfr[j][s] = *(const v8s*)(pb + NH*8192 + ((((wn*2 + j)*2 + s) << 9) | rswz));
}

template<int MH, int NH>
__device__ __forceinline__ void mfma16(v4f acc[8][4], v8s af[4][2], v8s bfr[2][2])
{
  __builtin_amdgcn_s_setprio(1);
#pragma unroll
  for (int i = 0; i < 4; ++i)
#pragma unroll
    for (int j = 0; j < 2; ++j)
#pragma unroll
      for (int s = 0; s < 2; ++s)
        acc[MH*4+i][NH*2+j] = __builtin_amdgcn_mfma_f32_16x16x32_bf16(
            af[i][s], bfr[j][s], acc[MH*4+i][NH*2+j], 0, 0, 0);
  __builtin_amdgcn_s_setprio(0);
}

#define STAGE(G, LD, LDSBASE, GROW0, KT) do { \
    gload16((G) + (long long)((GROW0) + sRow) * (LD) + (KT) + sCol, \
            (LDSBASE) + w512); \
    gload16((G) + (long long)((GROW0) + 64 + sRow) * (LD) + (KT) + sCol, \
            (LDSBASE) + 4096 + w512); \
  } while (0)

template<int EPI>
__global__ __launch_bounds__(512, 2)
void gemm256(const unsigned short* __restrict__ A, int lda,
             const unsigned short* __restrict__ Bt, int ldb,
             const float* __restrict__ bias,
             void* __restrict__ out0, unsigned short* __restrict__ pbs,
             int kLen, const float* __restrict__ gates)
{
  __shared__ __align__(16) unsigned short lds[65536];   // 128 KiB
  unsigned short* As0 = lds;
  unsigned short* As1 = lds + 16384;
  unsigned short* Bs0 = lds + 32768;
  unsigned short* Bs1 = lds + 49152;

  const int tid  = threadIdx.x;
  const int lane = tid & 63;
  const int w    = tid >> 6;        // 0..7
  const int wm   = w >> 2;          // 0..1
  const int wn   = w & 3;           // 0..3
  const int m0   = blockIdx.y * 256;
  const int n0   = blockIdx.x * 256;
  const int z    = blockIdx.z;
  const int kBase = (EPI == 3) ? z * kLen : 0;

  const int sRow = (w >> 1) * 16 + (lane >> 2);
  const int sCol = (w & 1) * 32 + (((lane & 3) * 8) ^ (((lane >> 5) & 1) << 4));
  const int rr   = lane & 15;
  const int kgrp = lane >> 4;
  const int rswz = (rr * 32 + kgrp * 8) ^ ((rr & 8) << 1);
  const int w512 = w * 512;

  v4f acc[8][4] = {};
  v8s af[4][2], b0[2][2], b1[2][2];

  const int iters = kLen >> 7;   // 2 K-tiles (BK=64) per iteration

  // ---- prologue: buf0 full (8 gloads) + buf1 A-lo (2) ----
  STAGE(A,  lda, As0,        m0,       kBase);
  STAGE(A,  lda, As0 + 8192, m0 + 128, kBase);
  STAGE(Bt, ldb, Bs0,        n0,       kBase);
  STAGE(Bt, ldb, Bs0 + 8192, n0 + 128, kBase);
  STAGE(A,  lda, As1,        m0,       kBase + 64);
  VMC2;   // buf0 landed; buf1-Alo in flight
  BAR;

  for (int it = 0; it < iters; ++it) {
    const bool nl = (it != iters - 1);
    const int k0t = kBase + it * 128;
    const int kT1 = k0t + 64, kT2 = k0t + 128, kT3 = k0t + 192;

    // ph1: q(0,0) buf0 | stage Bs1-lo (T+1)
    read_a<0>(af, As0, wm, rswz);
    read_b<0>(b0, Bs0, wn, rswz);
    STAGE(Bt, ldb, Bs1, n0, kT1);
    mfma16<0,0>(acc, af, b0);
    BAR;
    // ph2: q(0,1) | stage Bs1-hi (T+1)
    read_b<1>(b1, Bs0, wn, rswz);
    STAGE(Bt, ldb, Bs1 + 8192, n0 + 128, kT1);
    mfma16<0,1>(acc, af, b1);
    BAR;
    // ph3: q(1,1) | stage As1-hi (T+1)
    read_a<1>(af, As0, wm, rswz);
    STAGE(A, lda, As1 + 8192, m0 + 128, kT1);
    mfma16<1,1>(acc, af, b1);
    BAR;
    // ph4: q(1,0) | stage As0-lo (T+2) | VMC: buf1 landed
    if (nl) STAGE(A, lda, As0, m0, kT2);
    mfma16<1,0>(acc, af, b0);
    if (nl) { VMC2; } else { VMC0; }
    BAR;
    // ph5: q(0,0) buf1 | stage Bs0-lo (T+2)
    read_a<0>(af, As1, wm, rswz);
    read_b<0>(b0, Bs1, wn, rswz);
    if (nl) STAGE(Bt, ldb, Bs0, n0, kT2);
    mfma16<0,0>(acc, af, b0);
    BAR;
    // ph6: q(0,1) | stage Bs0-hi (T+2)
    read_b<1>(b1, Bs1, wn, rswz);
    if (nl) STAGE(Bt, ldb, Bs0 + 8192, n0 + 128, kT2);
    mfma16<0,1>(acc, af, b1);
    BAR;
    // ph7: q(1,1) | stage As0-hi (T+2)
    read_a<1>(af, As1, wm, rswz);
    if (nl) STAGE(A, lda, As0 + 8192, m0 + 128, kT2);
    mfma16<1,1>(acc, af, b1);
    BAR;
    // ph8: q(1,0) | stage As1-lo (T+3) | VMC2: buf0(T+2) landed
    if (nl) STAGE(A, lda, As1, m0, kT3);
    mfma16<1,0>(acc, af, b0);
    if (nl) { VMC2; }
    BAR;
  }

  // ---- epilogue ----
  const int lr4 = (lane >> 4) * 4;
  const int lc  = lane & 15;
  float gate = 0.f;
  if (EPI == 1) gate = gates[(m0 >> 10) * 8 + (n0 >> 10)];

#pragma unroll
  for (int mi = 0; mi < 8; ++mi) {
    const int rowb = m0 + (mi >> 2) * 128 + wm * 64 + (mi & 3) * 16 + lr4;
#pragma unroll
    for (int nj = 0; nj < 4; ++nj) {
      const int col = n0 + (nj >> 1) * 128 + wn * 32 + (nj & 1) * 16 + lc;
#pragma unroll
      for (int r = 0; r < 4; ++r) {
        const int row = rowb + r;
        float v = acc[mi][nj][r];
        if (EPI == 0) {
          v += bias[col];
          const int which = col >> 10;
          ((unsigned short*)out0)[(long long)which * 4194304 + (long long)row * 1024 + (col & 1023)] = f2bu(v);
        } else if (EPI == 1) {
          v += bias[col];
          float u = 0.7978845608028654f * (v + 0.044715f * v * v * v);
          u = fminf(fmaxf(u, -15.f), 15.f);
          float e2 = __expf(2.f * u);
          float th = (e2 - 1.f) / (e2 + 1.f);
          ((unsigned short*)out0)[(long long)row * 8192 + col] = f2bu(gate * 0.5f * v * (1.f + th));
        } else {
          if (z == 0) ((float*)out0)[(long long)row * 1024 + col] = v;
          else pbs[(long long)(z - 1) * 4194304 + (long long)row * 1024 + col] = f2bu(v);
        }
      }
    }
  }
}

// ---------------------------------------------------------------------------
// out = out + pb0 + pb1 + pb2 (bf16 partials) + bias2[b][n]
// ---------------------------------------------------------------------------
__global__ __launch_bounds__(256)
void reduce3(float* __restrict__ out, const unsigned short* __restrict__ pb,
             const float* __restrict__ bias2)
{
  const int i = (blockIdx.x * 256 + threadIdx.x) * 4;
  const int b = i >> 20;
  const int n = i & 1023;
  float4 a = *(const float4*)(out + i);
  ushort4 p0 = *(const ushort4*)(pb + i);
  ushort4 p1 = *(const ushort4*)(pb + 4194304 + i);
  ushort4 p2 = *(const ushort4*)(pb + 8388608 + i);
  float4 bb = *(const float4*)(bias2 + b * 1024 + n);
  a.x += b2f(p0.x) + b2f(p1.x) + b2f(p2.x) + bb.x;
  a.y += b2f(p0.y) + b2f(p1.y) + b2f(p2.y) + bb.y;
  a.z += b2f(p0.z) + b2f(p1.z) + b2f(p2.z) + bb.z;
  a.w += b2f(p0.w) + b2f(p1.w) + b2f(p2.w) + bb.w;
  *(float4*)(out + i) = a;
}

// ---------------------------------------------------------------------------
// Per-token cross-head attention (unchanged)
// ---------------------------------------------------------------------------
__global__ __launch_bounds__(256)
void attn_kernel(const unsigned short* __restrict__ Qb,
                 const unsigned short* __restrict__ Kb,
                 const unsigned short* __restrict__ Vb,
                 unsigned short* __restrict__ a)
{
  const int token = blockIdx.x;
  const int b = token >> 10, s = token & 1023;
  __shared__ float Qs[16][65], Ks[16][65], Vs[16][65];
  __shared__ float attn_s[16][17];
  const int t = threadIdx.x;
  const long long base = (long long)token * 1024;

  {
    const int i0 = t * 4;
    const int hh = i0 >> 6, dd = i0 & 63;
    ushort4 qv = *(const ushort4*)(Qb + base + i0);
    ushort4 kv = *(const ushort4*)(Kb + base + i0);
    ushort4 vv = *(const ushort4*)(Vb + base + i0);
    Qs[hh][dd+0]=b2f(qv.x); Qs[hh][dd+1]=b2f(qv.y); Qs[hh][dd+2]=b2f(qv.z); Qs[hh][dd+3]=b2f(qv.w);
    Ks[hh][dd+0]=b2f(kv.x); Ks[hh][dd+1]=b2f(kv.y); Ks[hh][dd+2]=b2f(kv.z); Ks[hh][dd+3]=b2f(kv.w);
    Vs[hh][dd+0]=b2f(vv.x); Vs[hh][dd+1]=b2f(vv.y); Vs[hh][dd+2]=b2f(vv.z); Vs[hh][dd+3]=b2f(vv.w);
  }
  __syncthreads();

  const int q = t >> 4, k = t & 15;
  float sc = 0.f;
#pragma unroll
  for (int d = 0; d < 64; ++d) sc += Qs[q][d] * Ks[k][d];
  sc *= 0.125f;
  float mx = sc;
#pragma unroll
  for (int m = 1; m < 16; m <<= 1) mx = fmaxf(mx, __shfl_xor(mx, m, 64));
  float ex = __expf(sc - mx);
  float sum = ex;
#pragma unroll
  for (int m = 1; m < 16; m <<= 1) sum += __shfl_xor(sum, m, 64);
  attn_s[q][k] = ex / sum;
  __syncthreads();

  const int hd = t & 63;
  const int wv = t >> 6;
#pragma unroll
  for (int r = 0; r < 4; ++r) {
    const int qq = wv * 4 + r;
    float o = 0.f;
#pragma unroll
    for (int kk = 0; kk < 16; ++kk) o += attn_s[qq][kk] * Vs[kk][hd];
    a[(long long)b * 1048576 + (long long)(qq * 64 + (s >> 4)) * 1024 + (s & 15) * 64 + hd] = f2bu(o);
  }
}

// ---------------------------------------------------------------------------
// Gating helpers (unchanged)
// ---------------------------------------------------------------------------
__global__ __launch_bounds__(256)
void col_sum_part(const unsigned short* __restrict__ a, float* __restrict__ part)
{
  const int bx = blockIdx.x;
  const int b = bx >> 2;
  const int d = (bx & 3) * 256 + threadIdx.x;
  const int y = blockIdx.y;
  const unsigned short* p = a + (long long)b * 1048576 + (long long)y * 131072 + d;
  float s = 0.f;
  for (int i = 0; i < 128; ++i) s += b2f(p[i * 1024]);
  part[(y * 4 + b) * 1024 + d] = s;
}

__global__ __launch_bounds__(256)
void gates_bias2(const float* __restrict__ part,
                 const float* __restrict__ Wg,
                 const float* __restrict__ bg,
                 const float* __restrict__ b2,
                 float* __restrict__ gates,
                 float* __restrict__ bias2)
{
  __shared__ float am[4][1024];
  __shared__ float sg[4][8];
  const int t = threadIdx.x;

  for (int i = t; i < 4096; i += 256) {
    const int b = i >> 10, d = i & 1023;
    float s = 0.f;
#pragma unroll
    for (int y = 0; y < 8; ++y) s += part[(y * 4 + b) * 1024 + d];
    am[b][d] = s * (1.f / 1024.f);
  }
  __syncthreads();

  const int pair = t >> 3, subl = t & 7;
  const int b = pair >> 3, e = pair & 7;
  float s = 0.f;
  for (int d = subl * 128; d < subl * 128 + 128; ++d) s += am[b][d] * Wg[d * 8 + e];
#pragma unroll
  for (int m = 1; m < 8; m <<= 1) s += __shfl_xor(s, m, 64);
  if (subl == 0) sg[b][e] = s + bg[e];
  __syncthreads();

  if (t < 4) {
    float mx = -1e30f;
    for (int ee = 0; ee < 8; ++ee) mx = fmaxf(mx, sg[t][ee]);
    float g[8]; float ssum = 0.f;
    for (int ee = 0; ee < 8; ++ee) { g[ee] = __expf(sg[t][ee] - mx); ssum += g[ee]; }
    for (int ee = 0; ee < 8; ++ee) { sg[t][ee] = g[ee] / ssum; gates[t * 8 + ee] = sg[t][ee]; }
  }
  __syncthreads();

  for (int i = t; i < 4096; i += 256) {
    const int bb = i >> 10, n = i & 1023;
    float ss = 0.f;
#pragma unroll
    for (int ee = 0; ee < 8; ++ee) ss += sg[bb][ee] * b2[ee * 1024 + n];
    bias2[i] = ss;
  }
}

// ---------------------------------------------------------------------------
// Host launch
// ---------------------------------------------------------------------------
extern "C" void kernel_launch(void* const* d_in, const int* in_sizes, int n_in,
                              void* d_out, int out_size, void* d_ws, size_t ws_size,
                              hipStream_t stream) {
  const float* x  = (const float*)d_in[0];
  const float* Wq = (const float*)d_in[1];
  const float* bq = (const float*)d_in[2];
  const float* Wk = (const float*)d_in[3];
  const float* bk = (const float*)d_in[4];
  const float* Wv = (const float*)d_in[5];
  const float* bv = (const float*)d_in[6];
  const float* Wg = (const float*)d_in[7];
  const float* bg = (const float*)d_in[8];
  const float* W1 = (const float*)d_in[9];
  const float* b1 = (const float*)d_in[10];
  const float* W2 = (const float*)d_in[11];
  const float* b2 = (const float*)d_in[12];
  float* out = (float*)d_out;

  if (ws_size < (size_t)109300000) return;

  char* ws = (char*)d_ws;
  unsigned short* xb   = (unsigned short*)(ws + 0);
  unsigned short* Wqt  = (unsigned short*)(ws + 8388608);     // [3072][1024]
  unsigned short* Qb   = (unsigned short*)(ws + 14680064);    // Q,K,V [3][4096][1024]
  unsigned short* hs   = (unsigned short*)(ws + 0);           // [4096][8192]
  unsigned short* abuf = (unsigned short*)(ws + 67108864);    // [4096][1024]
  unsigned short* pbs  = (unsigned short*)(ws + 67108864);    // 3x[4096][1024] bf16 (after EPI1)
  unsigned short* W1t  = (unsigned short*)(ws + 75497472);    // [8192][1024]
  unsigned short* W2t  = (unsigned short*)(ws + 92274688);    // [1024][8192]
  float* part  = (float*)(ws + 109051904);
  float* gates = (float*)(ws + 109051904 + 131072);
  float* bias2 = (float*)(ws + 109051904 + 131072 + 512);
  float* bqkv  = (float*)(ws + 109051904 + 131072 + 512 + 16384);

  dim3 tb(256);

  transpose_cvt<<<dim3(16,16,1), tb, 0, stream>>>(Wq, 0LL, Wqt,           0LL, 1024, 1024, 1024);
  transpose_cvt<<<dim3(16,16,1), tb, 0, stream>>>(Wk, 0LL, Wqt + 1048576, 0LL, 1024, 1024, 1024);
  transpose_cvt<<<dim3(16,16,1), tb, 0, stream>>>(Wv, 0LL, Wqt + 2097152, 0LL, 1024, 1024, 1024);
  transpose_cvt<<<dim3(16,16,8), tb, 0, stream>>>(W1, 1048576LL, W1t, 1048576LL, 1024, 1024, 1024);
  transpose_cvt<<<dim3(16,16,8), tb, 0, stream>>>(W2, 1048576LL, W2t, 1024LL,    8192, 1024, 1024);
  cvt_f32_bf16<<<4096, tb, 0, stream>>>(x, xb, 4194304);
  hipMemcpyAsync(bqkv,        bq, 4096, hipMemcpyDeviceToDevice, stream);
  hipMemcpyAsync(bqkv + 1024, bk, 4096, hipMemcpyDeviceToDevice, stream);
  hipMemcpyAsync(bqkv + 2048, bv, 4096, hipMemcpyDeviceToDevice, stream);

  // QKV: M=4096, N=3072 (flat), K=1024
  gemm256<0><<<dim3(12,16,1), 512, 0, stream>>>(xb, 1024, Wqt, 1024, bqkv,
                                                Qb, nullptr, 1024, nullptr);
  // Attention -> scrambled a
  attn_kernel<<<4096, tb, 0, stream>>>(Qb, Qb + 4194304, Qb + 8388608, abuf);
  // Gating
  col_sum_part<<<dim3(16,8), tb, 0, stream>>>(abuf, part);
  gates_bias2<<<1, tb, 0, stream>>>(part, Wg, bg, b2, gates, bias2);
  // Expert up-proj + gelu + gate: M=4096, N=8192 (flat experts), K=1024
  gemm256<1><<<dim3(32,16,1), 512, 0, stream>>>(abuf, 1024, W1t, 1024, b1,
                                                hs, nullptr, 1024, gates);
  // Final down-proj: M=4096, N=1024, K=8192, split-K 4 (z=0 -> out f32, z>0 -> bf16 partials)
  gemm256<3><<<dim3(4,16,4), 512, 0, stream>>>(hs, 8192, W2t, 8192, nullptr,
                                               out, pbs, 2048, nullptr);
  reduce3<<<4096, tb, 0, stream>>>(out, pbs, bias2);
}

// Round 12
// 262.919 us; speedup vs baseline: 1.1423x; 1.0039x over previous
//
#include <hip/hip_runtime.h>
#include <stdint.h>

#define AS1 __attribute__((address_space(1)))
#define AS3 __attribute__((address_space(3)))

typedef short v8s __attribute__((ext_vector_type(8)));
typedef float v4f __attribute__((ext_vector_type(4)));

__device__ __forceinline__ float b2f(unsigned short u) {
  return __uint_as_float(((unsigned int)u) << 16);
}
__device__ __forceinline__ unsigned short f2bu(float f) {
  unsigned int u = __float_as_uint(f);
  u += 0x7fffu + ((u >> 16) & 1u);
  return (unsigned short)(u >> 16);
}

__device__ __forceinline__ void gload16(const void* g, const void* l) {
  __builtin_amdgcn_global_load_lds(
      (const AS1 void*)(uintptr_t)g,
      (AS3 void*)(unsigned)(uintptr_t)l,
      16, 0, 0);
}

#define BAR __builtin_amdgcn_s_barrier()
#define VMC2 asm volatile("s_waitcnt vmcnt(2)" ::: "memory")
#define VMC0 asm volatile("s_waitcnt vmcnt(0)" ::: "memory")

// ---------------------------------------------------------------------------
// All weight transposes in ONE launch. grid (16,16,19), 64x64 tiles.
// z in [0,3):  Wq/Wk/Wv -> Wqt + z*1M      (ld 1024)
// z in [3,11): W1[e]    -> W1t + e*1M      (ld 1024)
// z in [11,19):W2[e]    -> W2t + e*1024    (ld 8192)
// ---------------------------------------------------------------------------
__global__ __launch_bounds__(256)
void transpose_all(const float* __restrict__ wq, const float* __restrict__ wk,
                   const float* __restrict__ wv, const float* __restrict__ w1,
                   const float* __restrict__ w2,
                   unsigned short* __restrict__ Wqt,
                   unsigned short* __restrict__ W1t,
                   unsigned short* __restrict__ W2t)
{
  __shared__ float t[64][65];
  const int z = blockIdx.z;
  const float* src;
  unsigned short* dst;
  int ld;
  if (z < 3) {
    src = (z == 0) ? wq : (z == 1) ? wk : wv;
    dst = Wqt + (long long)z * 1048576;
    ld = 1024;
  } else if (z < 11) {
    src = w1 + (long long)(z - 3) * 1048576;
    dst = W1t + (long long)(z - 3) * 1048576;
    ld = 1024;
  } else {
    src = w2 + (long long)(z - 11) * 1048576;
    dst = W2t + (long long)(z - 11) * 1024;
    ld = 8192;
  }
  const int k0 = blockIdx.y * 64, n0 = blockIdx.x * 64;
  const int tr  = threadIdx.x >> 4;
  const int tc4 = (threadIdx.x & 15) * 4;
#pragma unroll
  for (int p = 0; p < 4; ++p) {
    float4 v = *(const float4*)(src + (long long)(k0 + tr + p * 16) * 1024 + n0 + tc4);
    t[tr + p * 16][tc4 + 0] = v.x;
    t[tr + p * 16][tc4 + 1] = v.y;
    t[tr + p * 16][tc4 + 2] = v.z;
    t[tr + p * 16][tc4 + 3] = v.w;
  }
  __syncthreads();
#pragma unroll
  for (int p = 0; p < 4; ++p) {
    const int n = tr + p * 16;
    ushort4 o;
    o.x = f2bu(t[tc4 + 0][n]);
    o.y = f2bu(t[tc4 + 1][n]);
    o.z = f2bu(t[tc4 + 2][n]);
    o.w = f2bu(t[tc4 + 3][n]);
    *(ushort4*)(dst + (long long)(n0 + n) * ld + k0 + tc4) = o;
  }
}

__global__ __launch_bounds__(256)
void cvt_f32_bf16(const float* __restrict__ src, unsigned short* __restrict__ dst, int n)
{
  const int i = (blockIdx.x * 256 + threadIdx.x) * 4;
  if (i >= n) return;
  float4 v = *(const float4*)(src + i);
  ushort4 o;
  o.x = f2bu(v.x); o.y = f2bu(v.y); o.z = f2bu(v.z); o.w = f2bu(v.w);
  *(ushort4*)(dst + i) = o;
}

// ---------------------------------------------------------------------------
// 256x256 bf16 GEMM, BK=64, 8 waves (2Mx4N), 8 phases / 2 K-tiles, single
// post-MFMA barrier per phase.  b1-HOIST: all B reads for a K-tile issue in
// ph1/ph5 (where the LDS pipe is otherwise idle for b1), so only ph3/ph7
// (af-hi) have same-phase read->MFMA exposure.  Reads-only-earlier vs R11,
// so the WAR/RAW ledger is strictly safer (VMC2@ph4/ph8 drains exactly the
// consumed buffer; >=1 barrier between every region's last read and restage).
// st_16x32-swizzled subtiled LDS; staging source pre-swizzled (rule 21).
// EPI 0: bf16 Q/K/V out = acc + bias[col]; out slab = col>>10
// EPI 1: bf16 out = gate * gelu_new(acc + bias[col])  (hs, ld 8192)
// EPI 3: split-K partial: z=0 -> f32 out0, z>0 -> bf16 pbs[z-1]
// ---------------------------------------------------------------------------
template<int MH>
__device__ __forceinline__ void read_a(v8s af[4][2],
    const unsigned short* pa, int wm, int rswz)
{
#pragma unroll
  for (int i = 0; i < 4; ++i)
#pragma unroll
    for (int s = 0; s < 2; ++s)
      af[i][s] = *(const v8s*)(pa + MH*8192 + ((((wm*4 + i)*2 + s) << 9) | rswz));
}

template<int NH>
__device__ __forceinline__ void read_b(v8s bfr[2][2],
    const unsigned short* pb, int wn, int rswz)
{
#pragma unroll
  for (int j = 0; j < 2; ++j)
#pragma unroll
    for (int s = 0; s < 2; ++s)
      bfr[j][s] = *(const v8s*)(pb + NH*8192 + ((((wn*2 + j)*2 + s) << 9) | rswz));
}

template<int MH, int NH>
__device__ __forceinline__ void mfma16(v4f acc[8][4], v8s af[4][2], v8s bfr[2][2])
{
  __builtin_amdgcn_s_setprio(1);
#pragma unroll
  for (int i = 0; i < 4; ++i)
#pragma unroll
    for (int j = 0; j < 2; ++j)
#pragma unroll
      for (int s = 0; s < 2; ++s)
        acc[MH*4+i][NH*2+j] = __builtin_amdgcn_mfma_f32_16x16x32_bf16(
            af[i][s], bfr[j][s], acc[MH*4+i][NH*2+j], 0, 0, 0);
  __builtin_amdgcn_s_setprio(0);
}

#define STAGE(G, LD, LDSBASE, GROW0, KT) do { \
    gload16((G) + (long long)((GROW0) + sRow) * (LD) + (KT) + sCol, \
            (LDSBASE) + w512); \
    gload16((G) + (long long)((GROW0) + 64 + sRow) * (LD) + (KT) + sCol, \
            (LDSBASE) + 4096 + w512); \
  } while (0)

template<int EPI>
__global__ __launch_bounds__(512, 2)
void gemm256(const unsigned short* __restrict__ A, int lda,
             const unsigned short* __restrict__ Bt, int ldb,
             const float* __restrict__ bias,
             void* __restrict__ out0, unsigned short* __restrict__ pbs,
             int kLen, const float* __restrict__ gates)
{
  __shared__ __align__(16) unsigned short lds[65536];   // 128 KiB
  unsigned short* As0 = lds;
  unsigned short* As1 = lds + 16384;
  unsigned short* Bs0 = lds + 32768;
  unsigned short* Bs1 = lds + 49152;

  const int tid  = threadIdx.x;
  const int lane = tid & 63;
  const int w    = tid >> 6;        // 0..7
  const int wm   = w >> 2;          // 0..1
  const int wn   = w & 3;           // 0..3
  const int m0   = blockIdx.y * 256;
  const int n0   = blockIdx.x * 256;
  const int z    = blockIdx.z;
  const int kBase = (EPI == 3) ? z * kLen : 0;

  const int sRow = (w >> 1) * 16 + (lane >> 2);
  const int sCol = (w & 1) * 32 + (((lane & 3) * 8) ^ (((lane >> 5) & 1) << 4));
  const int rr   = lane & 15;
  const int kgrp = lane >> 4;
  const int rswz = (rr * 32 + kgrp * 8) ^ ((rr & 8) << 1);
  const int w512 = w * 512;

  v4f acc[8][4] = {};
  v8s af[4][2], b0[2][2], b1[2][2];

  const int iters = kLen >> 7;   // 2 K-tiles (BK=64) per iteration

  // ---- prologue: buf0 full (8 gloads) + buf1 A-lo (2) ----
  STAGE(A,  lda, As0,        m0,       kBase);
  STAGE(A,  lda, As0 + 8192, m0 + 128, kBase);
  STAGE(Bt, ldb, Bs0,        n0,       kBase);
  STAGE(Bt, ldb, Bs0 + 8192, n0 + 128, kBase);
  STAGE(A,  lda, As1,        m0,       kBase + 64);
  VMC2;   // buf0 landed; buf1-Alo in flight
  BAR;

  for (int it = 0; it < iters; ++it) {
    const bool nl = (it != iters - 1);
    const int k0t = kBase + it * 128;
    const int kT1 = k0t + 64, kT2 = k0t + 128, kT3 = k0t + 192;

    // ph1: q(0,0) buf0 | reads af-lo, b0, b1 (all B for this K-tile) | stage Bs1-lo (T+1)
    read_a<0>(af, As0, wm, rswz);
    read_b<0>(b0, Bs0, wn, rswz);
    read_b<1>(b1, Bs0, wn, rswz);
    STAGE(Bt, ldb, Bs1, n0, kT1);
    mfma16<0,0>(acc, af, b0);
    BAR;
    // ph2: q(0,1) (no reads) | stage Bs1-hi (T+1)
    STAGE(Bt, ldb, Bs1 + 8192, n0 + 128, kT1);
    mfma16<0,1>(acc, af, b1);
    BAR;
    // ph3: q(1,1) | read af-hi | stage As1-hi (T+1)
    read_a<1>(af, As0, wm, rswz);
    STAGE(A, lda, As1 + 8192, m0 + 128, kT1);
    mfma16<1,1>(acc, af, b1);
    BAR;
    // ph4: q(1,0) (no reads) | stage As0-lo (T+2) | VMC: buf1 landed
    if (nl) STAGE(A, lda, As0, m0, kT2);
    mfma16<1,0>(acc, af, b0);
    if (nl) { VMC2; } else { VMC0; }
    BAR;
    // ph5: q(0,0) buf1 | reads af-lo, b0, b1 | stage Bs0-lo (T+2)
    read_a<0>(af, As1, wm, rswz);
    read_b<0>(b0, Bs1, wn, rswz);
    read_b<1>(b1, Bs1, wn, rswz);
    if (nl) STAGE(Bt, ldb, Bs0, n0, kT2);
    mfma16<0,0>(acc, af, b0);
    BAR;
    // ph6: q(0,1) | stage Bs0-hi (T+2)
    if (nl) STAGE(Bt, ldb, Bs0 + 8192, n0 + 128, kT2);
    mfma16<0,1>(acc, af, b1);
    BAR;
    // ph7: q(1,1) | read af-hi | stage As0-hi (T+2)
    read_a<1>(af, As1, wm, rswz);
    if (nl) STAGE(A, lda, As0 + 8192, m0 + 128, kT2);
    mfma16<1,1>(acc, af, b1);
    BAR;
    // ph8: q(1,0) | stage As1-lo (T+3) | VMC2: buf0(T+2) landed
    if (nl) STAGE(A, lda, As1, m0, kT3);
    mfma16<1,0>(acc, af, b0);
    if (nl) { VMC2; }
    BAR;
  }

  // ---- epilogue ----
  const int lr4 = (lane >> 4) * 4;
  const int lc  = lane & 15;
  float gate = 0.f;
  if (EPI == 1) gate = gates[(m0 >> 10) * 8 + (n0 >> 10)];

#pragma unroll
  for (int mi = 0; mi < 8; ++mi) {
    const int rowb = m0 + (mi >> 2) * 128 + wm * 64 + (mi & 3) * 16 + lr4;
#pragma unroll
    for (int nj = 0; nj < 4; ++nj) {
      const int col = n0 + (nj >> 1) * 128 + wn * 32 + (nj & 1) * 16 + lc;
#pragma unroll
      for (int r = 0; r < 4; ++r) {
        const int row = rowb + r;
        float v = acc[mi][nj][r];
        if (EPI == 0) {
          v += bias[col];
          const int which = col >> 10;
          ((unsigned short*)out0)[(long long)which * 4194304 + (long long)row * 1024 + (col & 1023)] = f2bu(v);
        } else if (EPI == 1) {
          v += bias[col];
          float u = 0.7978845608028654f * (v + 0.044715f * v * v * v);
          u = fminf(fmaxf(u, -15.f), 15.f);
          float e2 = __expf(2.f * u);
          float th = (e2 - 1.f) / (e2 + 1.f);
          ((unsigned short*)out0)[(long long)row * 8192 + col] = f2bu(gate * 0.5f * v * (1.f + th));
        } else {
          if (z == 0) ((float*)out0)[(long long)row * 1024 + col] = v;
          else pbs[(long long)(z - 1) * 4194304 + (long long)row * 1024 + col] = f2bu(v);
        }
      }
    }
  }
}

// ---------------------------------------------------------------------------
// out = out + pb0 + pb1 + pb2 (bf16 partials) + bias2[b][n]
// ---------------------------------------------------------------------------
__global__ __launch_bounds__(256)
void reduce3(float* __restrict__ out, const unsigned short* __restrict__ pb,
             const float* __restrict__ bias2)
{
  const int i = (blockIdx.x * 256 + threadIdx.x) * 4;
  const int b = i >> 20;
  const int n = i & 1023;
  float4 a = *(const float4*)(out + i);
  ushort4 p0 = *(const ushort4*)(pb + i);
  ushort4 p1 = *(const ushort4*)(pb + 4194304 + i);
  ushort4 p2 = *(const ushort4*)(pb + 8388608 + i);
  float4 bb = *(const float4*)(bias2 + b * 1024 + n);
  a.x += b2f(p0.x) + b2f(p1.x) + b2f(p2.x) + bb.x;
  a.y += b2f(p0.y) + b2f(p1.y) + b2f(p2.y) + bb.y;
  a.z += b2f(p0.z) + b2f(p1.z) + b2f(p2.z) + bb.z;
  a.w += b2f(p0.w) + b2f(p1.w) + b2f(p2.w) + bb.w;
  *(float4*)(out + i) = a;
}

// ---------------------------------------------------------------------------
// Per-token cross-head attention (unchanged)
// ---------------------------------------------------------------------------
__global__ __launch_bounds__(256)
void attn_kernel(const unsigned short* __restrict__ Qb,
                 const unsigned short* __restrict__ Kb,
                 const unsigned short* __restrict__ Vb,
                 unsigned short* __restrict__ a)
{
  const int token = blockIdx.x;
  const int b = token >> 10, s = token & 1023;
  __shared__ float Qs[16][65], Ks[16][65], Vs[16][65];
  __shared__ float attn_s[16][17];
  const int t = threadIdx.x;
  const long long base = (long long)token * 1024;

  {
    const int i0 = t * 4;
    const int hh = i0 >> 6, dd = i0 & 63;
    ushort4 qv = *(const ushort4*)(Qb + base + i0);
    ushort4 kv = *(const ushort4*)(Kb + base + i0);
    ushort4 vv = *(const ushort4*)(Vb + base + i0);
    Qs[hh][dd+0]=b2f(qv.x); Qs[hh][dd+1]=b2f(qv.y); Qs[hh][dd+2]=b2f(qv.z); Qs[hh][dd+3]=b2f(qv.w);
    Ks[hh][dd+0]=b2f(kv.x); Ks[hh][dd+1]=b2f(kv.y); Ks[hh][dd+2]=b2f(kv.z); Ks[hh][dd+3]=b2f(kv.w);
    Vs[hh][dd+0]=b2f(vv.x); Vs[hh][dd+1]=b2f(vv.y); Vs[hh][dd+2]=b2f(vv.z); Vs[hh][dd+3]=b2f(vv.w);
  }
  __syncthreads();

  const int q = t >> 4, k = t & 15;
  float sc = 0.f;
#pragma unroll
  for (int d = 0; d < 64; ++d) sc += Qs[q][d] * Ks[k][d];
  sc *= 0.125f;
  float mx = sc;
#pragma unroll
  for (int m = 1; m < 16; m <<= 1) mx = fmaxf(mx, __shfl_xor(mx, m, 64));
  float ex = __expf(sc - mx);
  float sum = ex;
#pragma unroll
  for (int m = 1; m < 16; m <<= 1) sum += __shfl_xor(sum, m, 64);
  attn_s[q][k] = ex / sum;
  __syncthreads();

  const int hd = t & 63;
  const int wv = t >> 6;
#pragma unroll
  for (int r = 0; r < 4; ++r) {
    const int qq = wv * 4 + r;
    float o = 0.f;
#pragma unroll
    for (int kk = 0; kk < 16; ++kk) o += attn_s[qq][kk] * Vs[kk][hd];
    a[(long long)b * 1048576 + (long long)(qq * 64 + (s >> 4)) * 1024 + (s & 15) * 64 + hd] = f2bu(o);
  }
}

// ---------------------------------------------------------------------------
// Partial column sums, vectorized ushort4: grid (4 batches, 8 row-chunks)
// ---------------------------------------------------------------------------
__global__ __launch_bounds__(256)
void col_sum_part(const unsigned short* __restrict__ a, float* __restrict__ part)
{
  const int b = blockIdx.x;
  const int y = blockIdx.y;
  const int d4 = threadIdx.x * 4;
  const unsigned short* p = a + (long long)b * 1048576 + (long long)y * 131072 + d4;
  float s0 = 0.f, s1 = 0.f, s2 = 0.f, s3 = 0.f;
  for (int i = 0; i < 128; ++i) {
    ushort4 v = *(const ushort4*)(p + i * 1024);
    s0 += b2f(v.x); s1 += b2f(v.y); s2 += b2f(v.z); s3 += b2f(v.w);
  }
  float* o = part + (y * 4 + b) * 1024 + d4;
  o[0] = s0; o[1] = s1; o[2] = s2; o[3] = s3;
}

__global__ __launch_bounds__(256)
void gates_bias2(const float* __restrict__ part,
                 const float* __restrict__ Wg,
                 const float* __restrict__ bg,
                 const float* __restrict__ b2,
                 float* __restrict__ gates,
                 float* __restrict__ bias2)
{
  __shared__ float am[4][1024];
  __shared__ float sg[4][8];
  const int t = threadIdx.x;

  for (int i = t; i < 4096; i += 256) {
    const int b = i >> 10, d = i & 1023;
    float s = 0.f;
#pragma unroll
    for (int y = 0; y < 8; ++y) s += part[(y * 4 + b) * 1024 + d];
    am[b][d] = s * (1.f / 1024.f);
  }
  __syncthreads();

  const int pair = t >> 3, subl = t & 7;
  const int b = pair >> 3, e = pair & 7;
  float s = 0.f;
  for (int d = subl * 128; d < subl * 128 + 128; ++d) s += am[b][d] * Wg[d * 8 + e];
#pragma unroll
  for (int m = 1; m < 8; m <<= 1) s += __shfl_xor(s, m, 64);
  if (subl == 0) sg[b][e] = s + bg[e];
  __syncthreads();

  if (t < 4) {
    float mx = -1e30f;
    for (int ee = 0; ee < 8; ++ee) mx = fmaxf(mx, sg[t][ee]);
    float g[8]; float ssum = 0.f;
    for (int ee = 0; ee < 8; ++ee) { g[ee] = __expf(sg[t][ee] - mx); ssum += g[ee]; }
    for (int ee = 0; ee < 8; ++ee) { sg[t][ee] = g[ee] / ssum; gates[t * 8 + ee] = sg[t][ee]; }
  }
  __syncthreads();

  for (int i = t; i < 4096; i += 256) {
    const int bb = i >> 10, n = i & 1023;
    float ss = 0.f;
#pragma unroll
    for (int ee = 0; ee < 8; ++ee) ss += sg[bb][ee] * b2[ee * 1024 + n];
    bias2[i] = ss;
  }
}

// ---------------------------------------------------------------------------
// Host launch
// ---------------------------------------------------------------------------
extern "C" void kernel_launch(void* const* d_in, const int* in_sizes, int n_in,
                              void* d_out, int out_size, void* d_ws, size_t ws_size,
                              hipStream_t stream) {
  const float* x  = (const float*)d_in[0];
  const float* Wq = (const float*)d_in[1];
  const float* bq = (const float*)d_in[2];
  const float* Wk = (const float*)d_in[3];
  const float* bk = (const float*)d_in[4];
  const float* Wv = (const float*)d_in[5];
  const float* bv = (const float*)d_in[6];
  const float* Wg = (const float*)d_in[7];
  const float* bg = (const float*)d_in[8];
  const float* W1 = (const float*)d_in[9];
  const float* b1 = (const float*)d_in[10];
  const float* W2 = (const float*)d_in[11];
  const float* b2 = (const float*)d_in[12];
  float* out = (float*)d_out;

  if (ws_size < (size_t)109300000) return;

  char* ws = (char*)d_ws;
  unsigned short* xb   = (unsigned short*)(ws + 0);
  unsigned short* Wqt  = (unsigned short*)(ws + 8388608);     // [3072][1024]
  unsigned short* Qb   = (unsigned short*)(ws + 14680064);    // Q,K,V [3][4096][1024]
  unsigned short* hs   = (unsigned short*)(ws + 0);           // [4096][8192]
  unsigned short* abuf = (unsigned short*)(ws + 67108864);    // [4096][1024]
  unsigned short* pbs  = (unsigned short*)(ws + 67108864);    // 3x[4096][1024] bf16 (after EPI1)
  unsigned short* W1t  = (unsigned short*)(ws + 75497472);    // [8192][1024]
  unsigned short* W2t  = (unsigned short*)(ws + 92274688);    // [1024][8192]
  float* part  = (float*)(ws + 109051904);
  float* gates = (float*)(ws + 109051904 + 131072);
  float* bias2 = (float*)(ws + 109051904 + 131072 + 512);
  float* bqkv  = (float*)(ws + 109051904 + 131072 + 512 + 16384);

  dim3 tb(256);

  // All weight transposes in one launch
  transpose_all<<<dim3(16,16,19), tb, 0, stream>>>(Wq, Wk, Wv, W1, W2, Wqt, W1t, W2t);
  cvt_f32_bf16<<<4096, tb, 0, stream>>>(x, xb, 4194304);
  hipMemcpyAsync(bqkv,        bq, 4096, hipMemcpyDeviceToDevice, stream);
  hipMemcpyAsync(bqkv + 1024, bk, 4096, hipMemcpyDeviceToDevice, stream);
  hipMemcpyAsync(bqkv + 2048, bv, 4096, hipMemcpyDeviceToDevice, stream);

  // QKV: M=4096, N=3072 (flat), K=1024
  gemm256<0><<<dim3(12,16,1), 512, 0, stream>>>(xb, 1024, Wqt, 1024, bqkv,
                                                Qb, nullptr, 1024, nullptr);
  // Attention -> scrambled a
  attn_kernel<<<4096, tb, 0, stream>>>(Qb, Qb + 4194304, Qb + 8388608, abuf);
  // Gating
  col_sum_part<<<dim3(4,8), tb, 0, stream>>>(abuf, part);
  gates_bias2<<<1, tb, 0, stream>>>(part, Wg, bg, b2, gates, bias2);
  // Expert up-proj + gelu + gate: M=4096, N=8192 (flat experts), K=1024
  gemm256<1><<<dim3(32,16,1), 512, 0, stream>>>(abuf, 1024, W1t, 1024, b1,
                                                hs, nullptr, 1024, gates);
  // Final down-proj: M=4096, N=1024, K=8192, split-K 4 (z=0 -> out f32, z>0 -> bf16 partials)
  gemm256<3><<<dim3(4,16,4), 512, 0, stream>>>(hs, 8192, W2t, 8192, nullptr,
                                               out, pbs, 2048, nullptr);
  reduce3<<<4096, tb, 0, stream>>>(out, pbs, bias2);
}